// Round 3
// baseline (393.713 us; speedup 1.0000x reference)
//
#include <hip/hip_runtime.h>

#define B_ 4
#define C_ 256
#define N_ 4096

typedef unsigned short u16;
typedef __bf16 bf16x8 __attribute__((ext_vector_type(8)));
typedef float f32x4 __attribute__((ext_vector_type(4)));
typedef u16 u16x8 __attribute__((ext_vector_type(8)));
typedef u16 u16x4 __attribute__((ext_vector_type(4)));

union BF8 { u16x8 u; bf16x8 b; };

__device__ __forceinline__ u16 f2bf(float f) {
  unsigned int u = __float_as_uint(f);
  u += 0x7fffu + ((u >> 16) & 1u);
  return (u16)(u >> 16);
}
__device__ __forceinline__ float bf2f(u16 u) {
  return __uint_as_float(((unsigned int)u) << 16);
}

__device__ __forceinline__ f32x4 mfma16(bf16x8 a, bf16x8 b, f32x4 c) {
  return __builtin_amdgcn_mfma_f32_16x16x32_bf16(a, b, c, 0, 0, 0);
}

// ---------------- x[b][c][n] fp32 -> Xt[b][n][c] bf16 ----------------
__global__ __launch_bounds__(256) void k_transpose(const float* __restrict__ x,
                                                   u16* __restrict__ Xt) {
  __shared__ u16 T[64 * 72];
  const int b = blockIdx.z, c0 = blockIdx.y * 64, n0 = blockIdx.x * 64;
  const int t = threadIdx.x;
#pragma unroll
  for (int it = 0; it < 4; ++it) {
    int chunk = t + 256 * it;
    int row = chunk >> 4;   // c-local 0..63
    int col = chunk & 15;   // float4 along n
    const float* g = x + (((size_t)b * C_ + c0 + row) * N_ + n0 + col * 4);
    f32x4 v = *(const f32x4*)g;
#pragma unroll
    for (int i = 0; i < 4; ++i) T[(col * 4 + i) * 72 + row] = f2bf(v[i]);
  }
  __syncthreads();
#pragma unroll
  for (int it = 0; it < 2; ++it) {
    int chunk = t + 256 * it;
    int row = chunk >> 3;   // n-local 0..63
    int col = chunk & 7;
    *(u16x8*)&Xt[((size_t)b * N_ + n0 + row) * C_ + c0 + col * 8] =
        *(const u16x8*)&T[row * 72 + col * 8];
  }
}

// ---------------- GEMM: Y[o][n] = W[o][:] . Xt[n][:] ----------------
// MODE 0: QKV projection (Q gets softmax scale * log2e folded in).
// MODE 1: out-proj; stages combined attention output (O0+O1)/(l0+l1) from
//         the two j-split partials, then fp32 store + bias + residual.
template <int MODE>
__global__ __launch_bounds__(256) void k_gemm(
    const float* __restrict__ Wg, const float* __restrict__ bias,
    const u16* __restrict__ Bt, u16* __restrict__ Qt, u16* __restrict__ Kt,
    u16* __restrict__ Vn, const float* __restrict__ xres,
    float* __restrict__ outp, const u16* __restrict__ Op,
    const float* __restrict__ Ml) {
  __shared__ u16 Xs[64 * 264];
  const int b = blockIdx.z, yo = blockIdx.y, n0 = blockIdx.x * 64;
  const int t = threadIdx.x, w = t >> 6, lane = t & 63, quad = lane >> 4,
            l16 = lane & 15;
  if (MODE == 0) {
#pragma unroll
    for (int it = 0; it < 8; ++it) {
      int chunk = t + 256 * it;
      int row = chunk >> 5, col = chunk & 31;
      *(u16x8*)&Xs[row * 264 + col * 8] =
          *(const u16x8*)&Bt[((size_t)b * N_ + n0 + row) * C_ + col * 8];
    }
  } else {
    const size_t TEN = (size_t)B_ * N_ * C_;
#pragma unroll
    for (int it = 0; it < 8; ++it) {
      int chunk = t + 256 * it;
      int row = chunk >> 5, col = chunk & 31;
      size_t rowg = (size_t)b * N_ + n0 + row;
      float f = 1.0f / (Ml[rowg] + Ml[(size_t)B_ * N_ + rowg]);
      size_t base = rowg * C_ + col * 8;
      u16x8 a0 = *(const u16x8*)&Op[base];
      u16x8 a1 = *(const u16x8*)&Op[TEN + base];
      u16x8 rr;
#pragma unroll
      for (int i = 0; i < 8; ++i)
        rr[i] = f2bf((bf2f(a0[i]) + bf2f(a1[i])) * f);
      *(u16x8*)&Xs[row * 264 + col * 8] = rr;
    }
  }
  __syncthreads();

  f32x4 acc[4];
#pragma unroll
  for (int jt = 0; jt < 4; ++jt) acc[jt] = (f32x4){0.f, 0.f, 0.f, 0.f};

  if (MODE == 0 && yo < 8) {
    BF8 afr[8];
    const u16* arow = &Xs[(w * 16 + l16) * 264 + quad * 8];
#pragma unroll
    for (int ks = 0; ks < 8; ++ks) afr[ks].u = *(const u16x8*)(arow + ks * 32);
#pragma unroll
    for (int jt = 0; jt < 4; ++jt) {
      const float* wrow = Wg + (size_t)(yo * 64 + 16 * jt + l16) * C_ + quad * 8;
#pragma unroll
      for (int ks = 0; ks < 8; ++ks) {
        f32x4 w0 = *(const f32x4*)(wrow + ks * 32);
        f32x4 w1 = *(const f32x4*)(wrow + ks * 32 + 4);
        BF8 bf;
#pragma unroll
        for (int i = 0; i < 4; ++i) {
          bf.u[i] = f2bf(w0[i]);
          bf.u[4 + i] = f2bf(w1[i]);
        }
        acc[jt] = mfma16(afr[ks].b, bf.b, acc[jt]);
      }
    }
    // Q: fold softmax scale (1/16) * log2e so attention uses bare exp2
    const float mult = (yo < 4) ? 0.09016844005556f : 1.0f;
    u16* dst = (yo < 4) ? Qt : Kt;
    const int olocal = (yo < 4) ? yo * 64 : yo * 64 - 256;
#pragma unroll
    for (int jt = 0; jt < 4; ++jt) {
      float bv = bias[yo * 64 + 16 * jt + l16];
#pragma unroll
      for (int r = 0; r < 4; ++r) {
        float v = (acc[jt][r] + bv) * mult;
        int ip = n0 + w * 16 + quad * 4 + r;
        dst[((size_t)b * N_ + ip) * C_ + olocal + 16 * jt + l16] = f2bf(v);
      }
    }
  } else {
    const int o0 = (MODE == 0) ? (yo - 8) * 64 + 512 : yo * 64;
    BF8 afr[8];
    const float* wrow = Wg + (size_t)(o0 + w * 16 + l16) * C_ + quad * 8;
#pragma unroll
    for (int ks = 0; ks < 8; ++ks) {
      f32x4 w0 = *(const f32x4*)(wrow + ks * 32);
      f32x4 w1 = *(const f32x4*)(wrow + ks * 32 + 4);
#pragma unroll
      for (int i = 0; i < 4; ++i) {
        afr[ks].u[i] = f2bf(w0[i]);
        afr[ks].u[4 + i] = f2bf(w1[i]);
      }
    }
#pragma unroll
    for (int jt = 0; jt < 4; ++jt) {
#pragma unroll
      for (int ks = 0; ks < 8; ++ks) {
        BF8 bfr;
        bfr.u = *(const u16x8*)&Xs[(16 * jt + l16) * 264 + ks * 32 + quad * 8];
        acc[jt] = mfma16(afr[ks].b, bfr.b, acc[jt]);
      }
    }
    float bv[4];
#pragma unroll
    for (int r = 0; r < 4; ++r) bv[r] = bias[o0 + w * 16 + quad * 4 + r];
    if (MODE == 0) {
#pragma unroll
      for (int jt = 0; jt < 4; ++jt)
#pragma unroll
        for (int r = 0; r < 4; ++r) {
          int cv = o0 - 512 + w * 16 + quad * 4 + r;
          int pix = n0 + 16 * jt + l16;
          Vn[((size_t)b * C_ + cv) * N_ + pix] = f2bf(acc[jt][r] + bv[r]);
        }
    } else {
#pragma unroll
      for (int jt = 0; jt < 4; ++jt)
#pragma unroll
        for (int r = 0; r < 4; ++r) {
          int oc = o0 + w * 16 + quad * 4 + r;
          int pix = n0 + 16 * jt + l16;
          size_t idx = ((size_t)b * C_ + oc) * N_ + pix;
          outp[idx] = acc[jt][r] + bv[r] + xres[idx];
        }
    }
  }
}

// ---------------- flash attention, fixed-max softmax, S^T orientation ------
// grid: 512 blocks. xcd = id&7 -> b = xcd>>1, jhalf = xcd&1 (XCD-local KV).
// S^T = K.Q^T via mfma(kf, qf): D[col=l16 -> m][row=quad*4+r -> j], so each
// lane owns 4 consecutive j of ONE m-row: Ps writes are b64, row-sum is
// in-lane + 2 shuffles. No max tracking (logits |s|<~3, exp2 safe).
// Writes unnormalized O (bf16) + l per row per split.
__global__ __launch_bounds__(256) void k_attn(const u16* __restrict__ Qt,
                                              const u16* __restrict__ Kt,
                                              const u16* __restrict__ Vn,
                                              u16* __restrict__ Op,
                                              float* __restrict__ Ml) {
  __shared__ u16 Ks[64 * 264];   // [j][c 256 + pad]  33 KB
  __shared__ u16 Vs[256 * 72];   // [c][j 64 + pad]   36 KB
  __shared__ u16 Ps[64 * 72];    // [m][j 64 + pad]    9 KB  (total 78 KB)
  const int id = blockIdx.x;
  const int xcd = id & 7;
  const int b = xcd >> 1;
  const int jh = xcd & 1;
  const int i0 = (id >> 3) * 64;
  const int t = threadIdx.x, w = t >> 6, lane = t & 63, quad = lane >> 4,
            l16 = lane & 15;

  BF8 qf[8];
  {
    const u16* qrow = Qt + ((size_t)b * N_ + i0 + w * 16 + l16) * C_ + quad * 8;
#pragma unroll
    for (int ks = 0; ks < 8; ++ks) qf[ks].u = *(const u16x8*)(qrow + ks * 32);
  }
  f32x4 o[16];
#pragma unroll
  for (int ct = 0; ct < 16; ++ct) o[ct] = (f32x4){0.f, 0.f, 0.f, 0.f};
  float l_i = 0.f;  // row-sum for row m = w*16 + l16 (dup across quads)

  const u16* kbase = Kt + (size_t)b * N_ * C_;
  const u16* vbase = Vn + (size_t)b * (size_t)C_ * N_;
  const int jbeg = jh * (N_ / 2), jend = jbeg + N_ / 2;

  for (int j0 = jbeg; j0 < jend; j0 += 64) {
    __syncthreads();  // prior-iteration LDS reads done
#pragma unroll
    for (int it = 0; it < 8; ++it) {  // stage V tile [256 c][64 j]
      int chunk = t + 256 * it;
      int row = chunk >> 3, col = chunk & 7;
      *(u16x8*)&Vs[row * 72 + col * 8] =
          *(const u16x8*)&vbase[(size_t)row * N_ + j0 + col * 8];
    }
#pragma unroll
    for (int it = 0; it < 8; ++it) {  // stage K tile [64 j][256 c]
      int chunk = t + 256 * it;
      int row = chunk >> 5, col = chunk & 31;
      *(u16x8*)&Ks[row * 264 + col * 8] =
          *(const u16x8*)&kbase[(size_t)(j0 + row) * C_ + col * 8];
    }
    __syncthreads();

    // S^T: rows j = 16jt + quad*4 + r, col m = l16
    f32x4 s[4];
#pragma unroll
    for (int jt = 0; jt < 4; ++jt) s[jt] = (f32x4){0.f, 0.f, 0.f, 0.f};
#pragma unroll
    for (int jt = 0; jt < 4; ++jt)
#pragma unroll
      for (int ks = 0; ks < 8; ++ks) {
        BF8 kf;
        kf.u = *(const u16x8*)&Ks[(16 * jt + l16) * 264 + ks * 32 + quad * 8];
        s[jt] = mfma16(kf.b, qf[ks].b, s[jt]);
      }

    // p = exp2(s) (scale*log2e folded into Q); write b64 rows, sum in-lane
    float tile_sum = 0.f;
#pragma unroll
    for (int jt = 0; jt < 4; ++jt) {
      float p0 = exp2f(s[jt][0]), p1 = exp2f(s[jt][1]);
      float p2 = exp2f(s[jt][2]), p3 = exp2f(s[jt][3]);
      tile_sum += (p0 + p1) + (p2 + p3);
      u16x4 pk = {f2bf(p0), f2bf(p1), f2bf(p2), f2bf(p3)};
      *(u16x4*)&Ps[(w * 16 + l16) * 72 + 16 * jt + 4 * quad] = pk;
    }
    tile_sum += __shfl_xor(tile_sum, 16);
    tile_sum += __shfl_xor(tile_sum, 32);
    l_i += tile_sum;

    // O += P.V  (P rows are wave-private; V_lds is [c][j])
#pragma unroll
    for (int ks2 = 0; ks2 < 2; ++ks2) {
      BF8 pf;
      pf.u = *(const u16x8*)&Ps[(w * 16 + l16) * 72 + ks2 * 32 + quad * 8];
#pragma unroll
      for (int ct = 0; ct < 16; ++ct) {
        BF8 vf;
        vf.u = *(const u16x8*)&Vs[(16 * ct + l16) * 72 + ks2 * 32 + quad * 8];
        o[ct] = mfma16(pf.b, vf.b, o[ct]);
      }
    }
  }

  // write unnormalized O (bf16) + l per row
  u16* op = Op + ((size_t)jh * B_ + b) * (size_t)N_ * C_;
  float* ml = Ml + ((size_t)jh * B_ + b) * N_;
  if (quad == 0) ml[i0 + w * 16 + l16] = l_i;
#pragma unroll
  for (int ct = 0; ct < 16; ++ct)
#pragma unroll
    for (int r = 0; r < 4; ++r) {
      int ip = i0 + w * 16 + quad * 4 + r;
      op[(size_t)ip * C_ + 16 * ct + l16] = f2bf(o[ct][r]);
    }
}

extern "C" void kernel_launch(void* const* d_in, const int* in_sizes, int n_in,
                              void* d_out, int out_size, void* d_ws,
                              size_t ws_size, hipStream_t stream) {
  (void)in_sizes; (void)n_in; (void)out_size; (void)ws_size;
  const float* x = (const float*)d_in[0];
  const float* w_qkv = (const float*)d_in[1];
  const float* b_qkv = (const float*)d_in[2];
  const float* w_out = (const float*)d_in[3];
  const float* b_out = (const float*)d_in[4];
  float* outp = (float*)d_out;

  const size_t TENS = (size_t)B_ * N_ * C_;  // 4M elems
  u16* Xt = (u16*)d_ws;      // [B][N][C] bf16              8 MB
  u16* Qt = Xt + TENS;       // [B][N][C] bf16 (scaled)     8 MB
  u16* Kt = Qt + TENS;       // [B][N][C] bf16              8 MB
  u16* Vn = Kt + TENS;       // [B][C][N] bf16              8 MB
  u16* Op = Vn + TENS;       // [2][B][N][C] bf16          16 MB
  float* Ml = (float*)(Op + 2 * TENS);  // [2][B][N]       128 KB

  k_transpose<<<dim3(64, 4, 4), 256, 0, stream>>>(x, Xt);
  k_gemm<0><<<dim3(64, 12, 4), 256, 0, stream>>>(w_qkv, b_qkv, Xt, Qt, Kt, Vn,
                                                 nullptr, nullptr, nullptr,
                                                 nullptr);
  k_attn<<<dim3(512), 256, 0, stream>>>(Qt, Kt, Vn, Op, Ml);
  k_gemm<1><<<dim3(64, 4, 4), 256, 0, stream>>>(w_out, b_out, nullptr, nullptr,
                                                nullptr, nullptr, x, outp, Op,
                                                Ml);
}

// Round 4
// 247.008 us; speedup vs baseline: 1.5939x; 1.5939x over previous
//
#include <hip/hip_runtime.h>

#define B_ 4
#define C_ 256
#define N_ 4096

typedef unsigned short u16;
typedef __bf16 bf16x8 __attribute__((ext_vector_type(8)));
typedef float f32x4 __attribute__((ext_vector_type(4)));
typedef u16 u16x8 __attribute__((ext_vector_type(8)));
typedef u16 u16x4 __attribute__((ext_vector_type(4)));

union BF8 { u16x8 u; bf16x8 b; };

__device__ __forceinline__ u16 f2bf(float f) {
  unsigned int u = __float_as_uint(f);
  u += 0x7fffu + ((u >> 16) & 1u);
  return (u16)(u >> 16);
}
__device__ __forceinline__ float bf2f(u16 u) {
  return __uint_as_float(((unsigned int)u) << 16);
}

__device__ __forceinline__ f32x4 mfma16(bf16x8 a, bf16x8 b, f32x4 c) {
  return __builtin_amdgcn_mfma_f32_16x16x32_bf16(a, b, c, 0, 0, 0);
}

// ---------------- weights fp32 -> bf16 (once; kills per-block cvt) ---------
__global__ __launch_bounds__(256) void k_prep(const float* __restrict__ wq,
                                              const float* __restrict__ wo,
                                              u16* __restrict__ Wqb,
                                              u16* __restrict__ Wob) {
  int i = blockIdx.x * 256 + threadIdx.x;  // 65536 float4 chunks
  const int QCH = (3 * C_ * C_) / 4;       // 49152
  const float* src = (i < QCH) ? wq + (size_t)i * 4 : wo + (size_t)(i - QCH) * 4;
  u16* dst = (i < QCH) ? Wqb + (size_t)i * 4 : Wob + (size_t)(i - QCH) * 4;
  f32x4 v = *(const f32x4*)src;
  u16x4 r = {f2bf(v[0]), f2bf(v[1]), f2bf(v[2]), f2bf(v[3])};
  *(u16x4*)dst = r;
}

// ---------------- x[b][c][n] fp32 -> Xt[b][n][c] bf16 ----------------
__global__ __launch_bounds__(256) void k_transpose(const float* __restrict__ x,
                                                   u16* __restrict__ Xt) {
  __shared__ u16 T[64 * 72];
  const int b = blockIdx.z, c0 = blockIdx.y * 64, n0 = blockIdx.x * 64;
  const int t = threadIdx.x;
#pragma unroll
  for (int it = 0; it < 4; ++it) {
    int chunk = t + 256 * it;
    int row = chunk >> 4;   // c-local 0..63
    int col = chunk & 15;   // float4 along n
    const float* g = x + (((size_t)b * C_ + c0 + row) * N_ + n0 + col * 4);
    f32x4 v = *(const f32x4*)g;
#pragma unroll
    for (int i = 0; i < 4; ++i) T[(col * 4 + i) * 72 + row] = f2bf(v[i]);
  }
  __syncthreads();
#pragma unroll
  for (int it = 0; it < 2; ++it) {
    int chunk = t + 256 * it;
    int row = chunk >> 3;   // n-local 0..63
    int col = chunk & 7;
    *(u16x8*)&Xt[((size_t)b * N_ + n0 + row) * C_ + c0 + col * 8] =
        *(const u16x8*)&T[row * 72 + col * 8];
  }
}

// ---------------- GEMM: Y[o][n] = W[o][:] . Xt[n][:] ----------------
// MODE 0: QKV projection (Q gets softmax scale * log2e folded in).
// MODE 1: out-proj; stages combined attention output (O0+O1)/(l0+l1) from
//         the two j-split partials, then fp32 store + bias + residual.
template <int MODE>
__global__ __launch_bounds__(256) void k_gemm(
    const u16* __restrict__ Wb, const float* __restrict__ bias,
    const u16* __restrict__ Bt, u16* __restrict__ Qt, u16* __restrict__ Kt,
    u16* __restrict__ Vn, const float* __restrict__ xres,
    float* __restrict__ outp, const u16* __restrict__ Op,
    const float* __restrict__ Ml) {
  __shared__ u16 Xs[64 * 264];
  const int b = blockIdx.z, yo = blockIdx.y, n0 = blockIdx.x * 64;
  const int t = threadIdx.x, w = t >> 6, lane = t & 63, quad = lane >> 4,
            l16 = lane & 15;
  if (MODE == 0) {
#pragma unroll
    for (int it = 0; it < 8; ++it) {
      int chunk = t + 256 * it;
      int row = chunk >> 5, col = chunk & 31;
      *(u16x8*)&Xs[row * 264 + col * 8] =
          *(const u16x8*)&Bt[((size_t)b * N_ + n0 + row) * C_ + col * 8];
    }
  } else {
    const size_t TEN = (size_t)B_ * N_ * C_;
#pragma unroll
    for (int it = 0; it < 8; ++it) {
      int chunk = t + 256 * it;
      int row = chunk >> 5, col = chunk & 31;
      size_t rowg = (size_t)b * N_ + n0 + row;
      float f = 1.0f / (Ml[rowg] + Ml[(size_t)B_ * N_ + rowg]);
      size_t base = rowg * C_ + col * 8;
      u16x8 a0 = *(const u16x8*)&Op[base];
      u16x8 a1 = *(const u16x8*)&Op[TEN + base];
      u16x8 rr;
#pragma unroll
      for (int i = 0; i < 8; ++i)
        rr[i] = f2bf((bf2f(a0[i]) + bf2f(a1[i])) * f);
      *(u16x8*)&Xs[row * 264 + col * 8] = rr;
    }
  }
  __syncthreads();

  f32x4 acc[4];
#pragma unroll
  for (int jt = 0; jt < 4; ++jt) acc[jt] = (f32x4){0.f, 0.f, 0.f, 0.f};

  if (MODE == 0 && yo < 8) {
    // A = Xt rows (LDS), B = W rows (bf16 global, pre-converted)
    BF8 afr[8];
    const u16* arow = &Xs[(w * 16 + l16) * 264 + quad * 8];
#pragma unroll
    for (int ks = 0; ks < 8; ++ks) afr[ks].u = *(const u16x8*)(arow + ks * 32);
#pragma unroll
    for (int jt = 0; jt < 4; ++jt) {
      const u16* wrow = Wb + (size_t)(yo * 64 + 16 * jt + l16) * C_ + quad * 8;
#pragma unroll
      for (int ks = 0; ks < 8; ++ks) {
        BF8 bf;
        bf.u = *(const u16x8*)(wrow + ks * 32);
        acc[jt] = mfma16(afr[ks].b, bf.b, acc[jt]);
      }
    }
    // Q: fold softmax scale (1/16) * log2e so attention uses bare exp2
    const float mult = (yo < 4) ? 0.09016844005556f : 1.0f;
    u16* dst = (yo < 4) ? Qt : Kt;
    const int olocal = (yo < 4) ? yo * 64 : yo * 64 - 256;
#pragma unroll
    for (int jt = 0; jt < 4; ++jt) {
      float bv = bias[yo * 64 + 16 * jt + l16];
#pragma unroll
      for (int r = 0; r < 4; ++r) {
        float v = (acc[jt][r] + bv) * mult;
        int ip = n0 + w * 16 + quad * 4 + r;
        dst[((size_t)b * N_ + ip) * C_ + olocal + 16 * jt + l16] = f2bf(v);
      }
    }
  } else {
    const int o0 = (MODE == 0) ? (yo - 8) * 64 + 512 : yo * 64;
    BF8 afr[8];
    const u16* wrow = Wb + (size_t)(o0 + w * 16 + l16) * C_ + quad * 8;
#pragma unroll
    for (int ks = 0; ks < 8; ++ks) afr[ks].u = *(const u16x8*)(wrow + ks * 32);
#pragma unroll
    for (int jt = 0; jt < 4; ++jt) {
#pragma unroll
      for (int ks = 0; ks < 8; ++ks) {
        BF8 bfr;
        bfr.u = *(const u16x8*)&Xs[(16 * jt + l16) * 264 + ks * 32 + quad * 8];
        acc[jt] = mfma16(afr[ks].b, bfr.b, acc[jt]);
      }
    }
    float bv[4];
#pragma unroll
    for (int r = 0; r < 4; ++r) bv[r] = bias[o0 + w * 16 + quad * 4 + r];
    if (MODE == 0) {
#pragma unroll
      for (int jt = 0; jt < 4; ++jt)
#pragma unroll
        for (int r = 0; r < 4; ++r) {
          int cv = o0 - 512 + w * 16 + quad * 4 + r;
          int pix = n0 + 16 * jt + l16;
          Vn[((size_t)b * C_ + cv) * N_ + pix] = f2bf(acc[jt][r] + bv[r]);
        }
    } else {
#pragma unroll
      for (int jt = 0; jt < 4; ++jt)
#pragma unroll
        for (int r = 0; r < 4; ++r) {
          int oc = o0 + w * 16 + quad * 4 + r;
          int pix = n0 + 16 * jt + l16;
          size_t idx = ((size_t)b * C_ + oc) * N_ + pix;
          outp[idx] = acc[jt][r] + bv[r] + xres[idx];
        }
    }
  }
}

// ---------------- flash attention, reg-double-buffered staging -------------
// grid: 512 blocks. xcd = id&7 -> b = xcd>>1, jhalf = xcd&1 (XCD-local KV).
// Pipeline: issue next tile's global loads into VGPRs BEFORE computing on the
// current LDS tile; after the read-barrier just ds_write + barrier. Hides
// ~200-400cyc L2 latency behind ~6k cyc of compute.
__global__ __launch_bounds__(256, 2) void k_attn(const u16* __restrict__ Qt,
                                                 const u16* __restrict__ Kt,
                                                 const u16* __restrict__ Vn,
                                                 u16* __restrict__ Op,
                                                 float* __restrict__ Ml) {
  __shared__ u16 Ks[64 * 264];   // [j][c 256 + pad]  33 KB
  __shared__ u16 Vs[256 * 72];   // [c][j 64 + pad]   36 KB
  __shared__ u16 Ps[64 * 72];    // [m][j 64 + pad]    9 KB  (total 78 KB)
  const int id = blockIdx.x;
  const int xcd = id & 7;
  const int b = xcd >> 1;
  const int jh = xcd & 1;
  const int i0 = (id >> 3) * 64;
  const int t = threadIdx.x, w = t >> 6, lane = t & 63, quad = lane >> 4,
            l16 = lane & 15;

  BF8 qf[8];
  {
    const u16* qrow = Qt + ((size_t)b * N_ + i0 + w * 16 + l16) * C_ + quad * 8;
#pragma unroll
    for (int ks = 0; ks < 8; ++ks) qf[ks].u = *(const u16x8*)(qrow + ks * 32);
  }
  f32x4 o[16];
#pragma unroll
  for (int ct = 0; ct < 16; ++ct) o[ct] = (f32x4){0.f, 0.f, 0.f, 0.f};
  float l_i = 0.f;  // row-sum for row m = w*16 + l16 (dup across quads)

  const u16* kbase = Kt + (size_t)b * N_ * C_;
  const u16* vbase = Vn + (size_t)b * (size_t)C_ * N_;
  const int jbeg = jh * (N_ / 2), jend = jbeg + N_ / 2;

  // per-thread staging coordinates
  const int vrow = t >> 3, vcol = (t & 7) * 8;    // V rows vrow+32*it
  const int krow = t >> 5, kcol = (t & 31) * 8;   // K rows krow+8*it
  u16x8 pv[8], pk[8];  // 64 VGPRs of prefetch

  auto issue = [&](int j0) {
#pragma unroll
    for (int it = 0; it < 8; ++it)
      pv[it] = *(const u16x8*)&vbase[(size_t)(vrow + 32 * it) * N_ + j0 + vcol];
#pragma unroll
    for (int it = 0; it < 8; ++it)
      pk[it] = *(const u16x8*)&kbase[(size_t)(j0 + krow + 8 * it) * C_ + kcol];
  };
  auto commit = [&]() {
#pragma unroll
    for (int it = 0; it < 8; ++it)
      *(u16x8*)&Vs[(vrow + 32 * it) * 72 + vcol] = pv[it];
#pragma unroll
    for (int it = 0; it < 8; ++it)
      *(u16x8*)&Ks[(krow + 8 * it) * 264 + kcol] = pk[it];
  };

  issue(jbeg);
  commit();
  __syncthreads();

  for (int j0 = jbeg; j0 < jend; j0 += 64) {
    int jn = j0 + 64;
    if (jn >= jend) jn = jbeg;  // last iter: dummy (valid) prefetch
    issue(jn);

    // S^T: rows j = 16jt + quad*4 + r, col m = l16
    f32x4 s[4];
#pragma unroll
    for (int jt = 0; jt < 4; ++jt) s[jt] = (f32x4){0.f, 0.f, 0.f, 0.f};
#pragma unroll
    for (int jt = 0; jt < 4; ++jt)
#pragma unroll
      for (int ks = 0; ks < 8; ++ks) {
        BF8 kf;
        kf.u = *(const u16x8*)&Ks[(16 * jt + l16) * 264 + ks * 32 + quad * 8];
        s[jt] = mfma16(kf.b, qf[ks].b, s[jt]);
      }

    // p = exp2(s) (scale*log2e folded into Q); b64 row writes, in-lane sum
    float tile_sum = 0.f;
#pragma unroll
    for (int jt = 0; jt < 4; ++jt) {
      float p0 = exp2f(s[jt][0]), p1 = exp2f(s[jt][1]);
      float p2 = exp2f(s[jt][2]), p3 = exp2f(s[jt][3]);
      tile_sum += (p0 + p1) + (p2 + p3);
      u16x4 pkk = {f2bf(p0), f2bf(p1), f2bf(p2), f2bf(p3)};
      *(u16x4*)&Ps[(w * 16 + l16) * 72 + 16 * jt + 4 * quad] = pkk;
    }
    tile_sum += __shfl_xor(tile_sum, 16);
    tile_sum += __shfl_xor(tile_sum, 32);
    l_i += tile_sum;

    // O += P.V  (P rows wave-private; V_lds is [c][j])
#pragma unroll
    for (int ks2 = 0; ks2 < 2; ++ks2) {
      BF8 pf;
      pf.u = *(const u16x8*)&Ps[(w * 16 + l16) * 72 + ks2 * 32 + quad * 8];
#pragma unroll
      for (int ct = 0; ct < 16; ++ct) {
        BF8 vf;
        vf.u = *(const u16x8*)&Vs[(16 * ct + l16) * 72 + ks2 * 32 + quad * 8];
        o[ct] = mfma16(pf.b, vf.b, o[ct]);
      }
    }

    __syncthreads();  // all waves done reading tile j0
    commit();         // write tile jn (vmcnt drain happens here)
    __syncthreads();  // tile jn visible
  }

  // write unnormalized O (bf16) + l per row
  u16* op = Op + ((size_t)jh * B_ + b) * (size_t)N_ * C_;
  float* ml = Ml + ((size_t)jh * B_ + b) * N_;
  if (quad == 0) ml[i0 + w * 16 + l16] = l_i;
#pragma unroll
  for (int ct = 0; ct < 16; ++ct)
#pragma unroll
    for (int r = 0; r < 4; ++r) {
      int ip = i0 + w * 16 + quad * 4 + r;
      op[(size_t)ip * C_ + 16 * ct + l16] = f2bf(o[ct][r]);
    }
}

extern "C" void kernel_launch(void* const* d_in, const int* in_sizes, int n_in,
                              void* d_out, int out_size, void* d_ws,
                              size_t ws_size, hipStream_t stream) {
  (void)in_sizes; (void)n_in; (void)out_size; (void)ws_size;
  const float* x = (const float*)d_in[0];
  const float* w_qkv = (const float*)d_in[1];
  const float* b_qkv = (const float*)d_in[2];
  const float* w_out = (const float*)d_in[3];
  const float* b_out = (const float*)d_in[4];
  float* outp = (float*)d_out;

  const size_t TENS = (size_t)B_ * N_ * C_;  // 4M elems
  u16* Xt = (u16*)d_ws;      // [B][N][C] bf16              8 MB
  u16* Qt = Xt + TENS;       // [B][N][C] bf16 (scaled)     8 MB
  u16* Kt = Qt + TENS;       // [B][N][C] bf16              8 MB
  u16* Vn = Kt + TENS;       // [B][C][N] bf16              8 MB
  u16* Op = Vn + TENS;       // [2][B][N][C] bf16          16 MB
  float* Ml = (float*)(Op + 2 * TENS);       // [2][B][N]  128 KB
  u16* Wqb = (u16*)(Ml + 2 * B_ * N_);       // [3C][C]    384 KB
  u16* Wob = Wqb + 3 * C_ * C_;              // [C][C]     128 KB

  k_prep<<<dim3(256), 256, 0, stream>>>(w_qkv, w_out, Wqb, Wob);
  k_transpose<<<dim3(64, 4, 4), 256, 0, stream>>>(x, Xt);
  k_gemm<0><<<dim3(64, 12, 4), 256, 0, stream>>>(Wqb, b_qkv, Xt, Qt, Kt, Vn,
                                                 nullptr, nullptr, nullptr,
                                                 nullptr);
  k_attn<<<dim3(512), 256, 0, stream>>>(Qt, Kt, Vn, Op, Ml);
  k_gemm<1><<<dim3(64, 4, 4), 256, 0, stream>>>(Wob, b_out, nullptr, nullptr,
                                                nullptr, nullptr, x, outp, Op,
                                                Ml);
}

// Round 5
// 225.775 us; speedup vs baseline: 1.7438x; 1.0940x over previous
//
#include <hip/hip_runtime.h>

#define B_ 4
#define C_ 256
#define N_ 4096

typedef unsigned short u16;
typedef __bf16 bf16x8 __attribute__((ext_vector_type(8)));
typedef float f32x4 __attribute__((ext_vector_type(4)));
typedef float f32x16 __attribute__((ext_vector_type(16)));
typedef u16 u16x8 __attribute__((ext_vector_type(8)));
typedef u16 u16x4 __attribute__((ext_vector_type(4)));

union BF8 { u16x8 u; bf16x8 b; };

__device__ __forceinline__ u16 f2bf(float f) {
  unsigned int u = __float_as_uint(f);
  u += 0x7fffu + ((u >> 16) & 1u);
  return (u16)(u >> 16);
}
__device__ __forceinline__ float bf2f(u16 u) {
  return __uint_as_float(((unsigned int)u) << 16);
}

__device__ __forceinline__ f32x4 mfma16(bf16x8 a, bf16x8 b, f32x4 c) {
  return __builtin_amdgcn_mfma_f32_16x16x32_bf16(a, b, c, 0, 0, 0);
}
__device__ __forceinline__ f32x16 mfma32(bf16x8 a, bf16x8 b, f32x16 c) {
  return __builtin_amdgcn_mfma_f32_32x32x16_bf16(a, b, c, 0, 0, 0);
}

// ---------------- weights fp32 -> bf16 (once) ---------
__global__ __launch_bounds__(256) void k_prep(const float* __restrict__ wq,
                                              const float* __restrict__ wo,
                                              u16* __restrict__ Wqb,
                                              u16* __restrict__ Wob) {
  int i = blockIdx.x * 256 + threadIdx.x;  // 65536 float4 chunks
  const int QCH = (3 * C_ * C_) / 4;       // 49152
  const float* src = (i < QCH) ? wq + (size_t)i * 4 : wo + (size_t)(i - QCH) * 4;
  u16* dst = (i < QCH) ? Wqb + (size_t)i * 4 : Wob + (size_t)(i - QCH) * 4;
  f32x4 v = *(const f32x4*)src;
  u16x4 r = {f2bf(v[0]), f2bf(v[1]), f2bf(v[2]), f2bf(v[3])};
  *(u16x4*)dst = r;
}

// ---------------- x[b][c][n] fp32 -> Xt[b][n][c] bf16 ----------------
__global__ __launch_bounds__(256) void k_transpose(const float* __restrict__ x,
                                                   u16* __restrict__ Xt) {
  __shared__ u16 T[64 * 72];
  const int b = blockIdx.z, c0 = blockIdx.y * 64, n0 = blockIdx.x * 64;
  const int t = threadIdx.x;
#pragma unroll
  for (int it = 0; it < 4; ++it) {
    int chunk = t + 256 * it;
    int row = chunk >> 4;   // c-local 0..63
    int col = chunk & 15;   // float4 along n
    const float* g = x + (((size_t)b * C_ + c0 + row) * N_ + n0 + col * 4);
    f32x4 v = *(const f32x4*)g;
#pragma unroll
    for (int i = 0; i < 4; ++i) T[(col * 4 + i) * 72 + row] = f2bf(v[i]);
  }
  __syncthreads();
#pragma unroll
  for (int it = 0; it < 2; ++it) {
    int chunk = t + 256 * it;
    int row = chunk >> 3;   // n-local 0..63
    int col = chunk & 7;
    *(u16x8*)&Xt[((size_t)b * N_ + n0 + row) * C_ + c0 + col * 8] =
        *(const u16x8*)&T[row * 72 + col * 8];
  }
}

// ---------------- GEMM: Y[o][n] = W[o][:] . Xt[n][:] ----------------
// MODE 0: QKV projection (Q gets softmax scale * log2e folded in).
// MODE 1: out-proj; stages combined attention output (O0+O1)/(sum of 4 l
//         partials) from the j-split partials, then fp32 + bias + residual.
template <int MODE>
__global__ __launch_bounds__(256) void k_gemm(
    const u16* __restrict__ Wb, const float* __restrict__ bias,
    const u16* __restrict__ Bt, u16* __restrict__ Qt, u16* __restrict__ Kt,
    u16* __restrict__ Vn, const float* __restrict__ xres,
    float* __restrict__ outp, const u16* __restrict__ Op,
    const float* __restrict__ Ml) {
  __shared__ u16 Xs[64 * 264];
  const int b = blockIdx.z, yo = blockIdx.y, n0 = blockIdx.x * 64;
  const int t = threadIdx.x, w = t >> 6, lane = t & 63, quad = lane >> 4,
            l16 = lane & 15;
  if (MODE == 0) {
#pragma unroll
    for (int it = 0; it < 8; ++it) {
      int chunk = t + 256 * it;
      int row = chunk >> 5, col = chunk & 31;
      *(u16x8*)&Xs[row * 264 + col * 8] =
          *(const u16x8*)&Bt[((size_t)b * N_ + n0 + row) * C_ + col * 8];
    }
  } else {
    const size_t TEN = (size_t)B_ * N_ * C_;
    const size_t BN = (size_t)B_ * N_;
#pragma unroll
    for (int it = 0; it < 8; ++it) {
      int chunk = t + 256 * it;
      int row = chunk >> 5, col = chunk & 31;
      size_t rowg = (size_t)b * N_ + n0 + row;
      float f = 1.0f / (Ml[rowg] + Ml[BN + rowg] + Ml[2 * BN + rowg] +
                        Ml[3 * BN + rowg]);
      size_t base = rowg * C_ + col * 8;
      u16x8 a0 = *(const u16x8*)&Op[base];
      u16x8 a1 = *(const u16x8*)&Op[TEN + base];
      u16x8 rr;
#pragma unroll
      for (int i = 0; i < 8; ++i)
        rr[i] = f2bf((bf2f(a0[i]) + bf2f(a1[i])) * f);
      *(u16x8*)&Xs[row * 264 + col * 8] = rr;
    }
  }
  __syncthreads();

  f32x4 acc[4];
#pragma unroll
  for (int jt = 0; jt < 4; ++jt) acc[jt] = (f32x4){0.f, 0.f, 0.f, 0.f};

  if (MODE == 0 && yo < 8) {
    // A = Xt rows (LDS), B = W rows (bf16 global, pre-converted)
    BF8 afr[8];
    const u16* arow = &Xs[(w * 16 + l16) * 264 + quad * 8];
#pragma unroll
    for (int ks = 0; ks < 8; ++ks) afr[ks].u = *(const u16x8*)(arow + ks * 32);
#pragma unroll
    for (int jt = 0; jt < 4; ++jt) {
      const u16* wrow = Wb + (size_t)(yo * 64 + 16 * jt + l16) * C_ + quad * 8;
#pragma unroll
      for (int ks = 0; ks < 8; ++ks) {
        BF8 bf;
        bf.u = *(const u16x8*)(wrow + ks * 32);
        acc[jt] = mfma16(afr[ks].b, bf.b, acc[jt]);
      }
    }
    // Q: fold softmax scale (1/16) * log2e so attention uses bare exp2
    const float mult = (yo < 4) ? 0.09016844005556f : 1.0f;
    u16* dst = (yo < 4) ? Qt : Kt;
    const int olocal = (yo < 4) ? yo * 64 : yo * 64 - 256;
#pragma unroll
    for (int jt = 0; jt < 4; ++jt) {
      float bv = bias[yo * 64 + 16 * jt + l16];
#pragma unroll
      for (int r = 0; r < 4; ++r) {
        float v = (acc[jt][r] + bv) * mult;
        int ip = n0 + w * 16 + quad * 4 + r;
        dst[((size_t)b * N_ + ip) * C_ + olocal + 16 * jt + l16] = f2bf(v);
      }
    }
  } else {
    const int o0 = (MODE == 0) ? (yo - 8) * 64 + 512 : yo * 64;
    BF8 afr[8];
    const u16* wrow = Wb + (size_t)(o0 + w * 16 + l16) * C_ + quad * 8;
#pragma unroll
    for (int ks = 0; ks < 8; ++ks) afr[ks].u = *(const u16x8*)(wrow + ks * 32);
#pragma unroll
    for (int jt = 0; jt < 4; ++jt) {
#pragma unroll
      for (int ks = 0; ks < 8; ++ks) {
        BF8 bfr;
        bfr.u = *(const u16x8*)&Xs[(16 * jt + l16) * 264 + ks * 32 + quad * 8];
        acc[jt] = mfma16(afr[ks].b, bfr.b, acc[jt]);
      }
    }
    float bv[4];
#pragma unroll
    for (int r = 0; r < 4; ++r) bv[r] = bias[o0 + w * 16 + quad * 4 + r];
    if (MODE == 0) {
#pragma unroll
      for (int jt = 0; jt < 4; ++jt)
#pragma unroll
        for (int r = 0; r < 4; ++r) {
          int cv = o0 - 512 + w * 16 + quad * 4 + r;
          int pix = n0 + 16 * jt + l16;
          Vn[((size_t)b * C_ + cv) * N_ + pix] = f2bf(acc[jt][r] + bv[r]);
        }
    } else {
#pragma unroll
      for (int jt = 0; jt < 4; ++jt)
#pragma unroll
        for (int r = 0; r < 4; ++r) {
          int oc = o0 + w * 16 + quad * 4 + r;
          int pix = n0 + 16 * jt + l16;
          size_t idx = ((size_t)b * C_ + oc) * N_ + pix;
          outp[idx] = acc[jt][r] + bv[r] + xres[idx];
        }
    }
  }
}

// ---------------- flash attention, 32x32x16 MFMA, reg-double-buffered ------
// grid: 512 blocks. xcd = id&7 -> b = xcd>>1, jhalf = xcd&1 (XCD-local KV).
// Wave layout: mh = w>>1 (q-row tile), jh2/nh = w&1.
//   QK: S^T(32x32) per wave via mfma32(kf, qf); lane owns q-col l32, 16 j regs
//       (j = (r&3)+8*(r>>2)+4*half). Row-sum fully in-lane + 1 shuffle.
//   P -> LDS (stride 68: 2-way-free b64 writes), barrier, PV reads full P.
//   PV: 4 acc tiles f32x16 (rows mh*32+, cols nh*128 + nt*32).
// l is 4 partial planes [jh][jh2]; summed in k_gemm<1>.
__global__ __launch_bounds__(256, 2) void k_attn(const u16* __restrict__ Qt,
                                                 const u16* __restrict__ Kt,
                                                 const u16* __restrict__ Vn,
                                                 u16* __restrict__ Op,
                                                 float* __restrict__ Ml) {
  __shared__ u16 Ks[64 * 264];   // [j][c 256 + pad]  33 KB
  __shared__ u16 Vs[256 * 72];   // [c][j 64 + pad]   36 KB
  __shared__ u16 Ps[64 * 68];    // [m][j 64 + pad]  8.5 KB (total ~78 KB)
  const int id = blockIdx.x;
  const int xcd = id & 7;
  const int b = xcd >> 1;
  const int jh = xcd & 1;
  const int i0 = (id >> 3) * 64;
  const int t = threadIdx.x, w = t >> 6, lane = t & 63;
  const int l32 = lane & 31, half = lane >> 5;
  const int mh = w >> 1, jh2 = w & 1, nh = w & 1;

  BF8 qf[16];
  {
    const u16* qrow =
        Qt + ((size_t)b * N_ + i0 + mh * 32 + l32) * C_ + half * 8;
#pragma unroll
    for (int ks = 0; ks < 16; ++ks) qf[ks].u = *(const u16x8*)(qrow + ks * 16);
  }
  f32x16 o[4];
#pragma unroll
  for (int nt = 0; nt < 4; ++nt)
#pragma unroll
    for (int r = 0; r < 16; ++r) o[nt][r] = 0.f;
  float l_i = 0.f;

  const u16* kbase = Kt + (size_t)b * N_ * C_;
  const u16* vbase = Vn + (size_t)b * (size_t)C_ * N_;
  const int jbeg = jh * (N_ / 2), jend = jbeg + N_ / 2;

  // per-thread staging coordinates
  const int vrow = t >> 3, vcol = (t & 7) * 8;    // V rows vrow+32*it
  const int krow = t >> 5, kcol = (t & 31) * 8;   // K rows krow+8*it
  u16x8 pv[8], pk[8];  // 64 VGPRs of prefetch

  auto issue = [&](int j0) {
#pragma unroll
    for (int it = 0; it < 8; ++it)
      pv[it] = *(const u16x8*)&vbase[(size_t)(vrow + 32 * it) * N_ + j0 + vcol];
#pragma unroll
    for (int it = 0; it < 8; ++it)
      pk[it] = *(const u16x8*)&kbase[(size_t)(j0 + krow + 8 * it) * C_ + kcol];
  };
  auto commit = [&]() {
#pragma unroll
    for (int it = 0; it < 8; ++it)
      *(u16x8*)&Vs[(vrow + 32 * it) * 72 + vcol] = pv[it];
#pragma unroll
    for (int it = 0; it < 8; ++it)
      *(u16x8*)&Ks[(krow + 8 * it) * 264 + kcol] = pk[it];
  };

  issue(jbeg);
  commit();
  __syncthreads();

  for (int j0 = jbeg; j0 < jend; j0 += 64) {
    int jn = j0 + 64;
    if (jn >= jend) jn = jbeg;  // last iter: dummy (valid) prefetch

    // S^T 32x32 tile: rows j (16 regs), cols q = l32
    f32x16 s;
#pragma unroll
    for (int r = 0; r < 16; ++r) s[r] = 0.f;
#pragma unroll
    for (int ks = 0; ks < 16; ++ks) {
      BF8 kf;
      kf.u = *(const u16x8*)&Ks[(jh2 * 32 + l32) * 264 + ks * 16 + half * 8];
      s = mfma32(kf.b, qf[ks].b, s);
    }

    issue(jn);  // prefetch latency hides behind exp + barrier + PV

    // p = exp2(s) (scale*log2e folded into Q); b64 row writes, in-lane sum
    float tile_sum = 0.f;
#pragma unroll
    for (int g = 0; g < 4; ++g) {
      float p0 = exp2f(s[4 * g + 0]), p1 = exp2f(s[4 * g + 1]);
      float p2 = exp2f(s[4 * g + 2]), p3 = exp2f(s[4 * g + 3]);
      tile_sum += (p0 + p1) + (p2 + p3);
      u16x4 pkk = {f2bf(p0), f2bf(p1), f2bf(p2), f2bf(p3)};
      // j = (r&3) + 8*(r>>2) + 4*half  ->  col jh2*32 + g*8 + 4*half + i
      *(u16x4*)&Ps[(mh * 32 + l32) * 68 + jh2 * 32 + g * 8 + 4 * half] = pkk;
    }
    tile_sum += __shfl_xor(tile_sum, 32);
    l_i += tile_sum;

    __syncthreads();  // Ps visible to all waves

    // O += P.V   (P 64x64 shared; V_lds is [c][j])
    BF8 pf[4];
#pragma unroll
    for (int ks = 0; ks < 4; ++ks)
      pf[ks].u = *(const u16x8*)&Ps[(mh * 32 + l32) * 68 + ks * 16 + half * 8];
#pragma unroll
    for (int nt = 0; nt < 4; ++nt) {
#pragma unroll
      for (int ks = 0; ks < 4; ++ks) {
        BF8 vf;
        vf.u = *(const u16x8*)&Vs[(nh * 128 + nt * 32 + l32) * 72 + ks * 16 +
                                  half * 8];
        o[nt] = mfma32(pf[ks].b, vf.b, o[nt]);
      }
    }

    __syncthreads();  // all waves done reading Ks/Vs/Ps
    commit();         // write tile jn
    __syncthreads();  // tile jn visible
  }

  // write unnormalized O (bf16) + l partial per (jh, jh2) plane
  u16* op = Op + ((size_t)jh * B_ + b) * (size_t)N_ * C_;
  float* ml = Ml + ((size_t)(jh * 2 + jh2) * B_ + b) * N_;
  if (lane < 32) ml[i0 + mh * 32 + l32] = l_i;
#pragma unroll
  for (int nt = 0; nt < 4; ++nt)
#pragma unroll
    for (int r = 0; r < 16; ++r) {
      int qrow = i0 + mh * 32 + (r & 3) + 8 * (r >> 2) + 4 * half;
      op[(size_t)qrow * C_ + nh * 128 + nt * 32 + l32] = f2bf(o[nt][r]);
    }
}

extern "C" void kernel_launch(void* const* d_in, const int* in_sizes, int n_in,
                              void* d_out, int out_size, void* d_ws,
                              size_t ws_size, hipStream_t stream) {
  (void)in_sizes; (void)n_in; (void)out_size; (void)ws_size;
  const float* x = (const float*)d_in[0];
  const float* w_qkv = (const float*)d_in[1];
  const float* b_qkv = (const float*)d_in[2];
  const float* w_out = (const float*)d_in[3];
  const float* b_out = (const float*)d_in[4];
  float* outp = (float*)d_out;

  const size_t TENS = (size_t)B_ * N_ * C_;  // 4M elems
  u16* Xt = (u16*)d_ws;      // [B][N][C] bf16              8 MB
  u16* Qt = Xt + TENS;       // [B][N][C] bf16 (scaled)     8 MB
  u16* Kt = Qt + TENS;       // [B][N][C] bf16              8 MB
  u16* Vn = Kt + TENS;       // [B][C][N] bf16              8 MB
  u16* Op = Vn + TENS;       // [2][B][N][C] bf16          16 MB
  float* Ml = (float*)(Op + 2 * TENS);       // [4][B][N]  256 KB
  u16* Wqb = (u16*)(Ml + 4 * (size_t)B_ * N_);  // [3C][C] 384 KB
  u16* Wob = Wqb + 3 * C_ * C_;                 // [C][C]  128 KB

  k_prep<<<dim3(256), 256, 0, stream>>>(w_qkv, w_out, Wqb, Wob);
  k_transpose<<<dim3(64, 4, 4), 256, 0, stream>>>(x, Xt);
  k_gemm<0><<<dim3(64, 12, 4), 256, 0, stream>>>(Wqb, b_qkv, Xt, Qt, Kt, Vn,
                                                 nullptr, nullptr, nullptr,
                                                 nullptr);
  k_attn<<<dim3(512), 256, 0, stream>>>(Qt, Kt, Vn, Op, Ml);
  k_gemm<1><<<dim3(64, 4, 4), 256, 0, stream>>>(Wob, b_out, nullptr, nullptr,
                                                nullptr, nullptr, x, outp, Op,
                                                Ml);
}

// Round 6
// 221.045 us; speedup vs baseline: 1.7811x; 1.0214x over previous
//
#include <hip/hip_runtime.h>

#define B_ 4
#define C_ 256
#define N_ 4096

typedef unsigned short u16;
typedef __bf16 bf16x8 __attribute__((ext_vector_type(8)));
typedef float f32x4 __attribute__((ext_vector_type(4)));
typedef float f32x16 __attribute__((ext_vector_type(16)));
typedef u16 u16x8 __attribute__((ext_vector_type(8)));
typedef u16 u16x4 __attribute__((ext_vector_type(4)));

union BF8 { u16x8 u; bf16x8 b; };

__device__ __forceinline__ u16 f2bf(float f) {
  unsigned int u = __float_as_uint(f);
  u += 0x7fffu + ((u >> 16) & 1u);
  return (u16)(u >> 16);
}
__device__ __forceinline__ float bf2f(u16 u) {
  return __uint_as_float(((unsigned int)u) << 16);
}

__device__ __forceinline__ f32x16 mfma32(bf16x8 a, bf16x8 b, f32x16 c) {
  return __builtin_amdgcn_mfma_f32_32x32x16_bf16(a, b, c, 0, 0, 0);
}

#define ROWMAP(r, half) (((r) & 3) + 8 * ((r) >> 2) + 4 * (half))

// ------- merged: x[b][c][n] fp32 -> Xt[b][n][c] bf16  +  weight fp32->bf16
__global__ __launch_bounds__(256) void k_pre(const float* __restrict__ x,
                                             u16* __restrict__ Xt,
                                             const float* __restrict__ wq,
                                             const float* __restrict__ wo,
                                             u16* __restrict__ Wqb,
                                             u16* __restrict__ Wob) {
  const int bid = blockIdx.x, t = threadIdx.x;
  if (bid < 1024) {
    __shared__ u16 T[64 * 72];
    const int n0 = (bid & 63) * 64, c0 = ((bid >> 6) & 3) * 64, b = bid >> 8;
#pragma unroll
    for (int it = 0; it < 4; ++it) {
      int chunk = t + 256 * it;
      int row = chunk >> 4;   // c-local
      int col = chunk & 15;   // float4 along n
      const float* g = x + (((size_t)b * C_ + c0 + row) * N_ + n0 + col * 4);
      f32x4 v = *(const f32x4*)g;
#pragma unroll
      for (int i = 0; i < 4; ++i) T[(col * 4 + i) * 72 + row] = f2bf(v[i]);
    }
    __syncthreads();
#pragma unroll
    for (int it = 0; it < 2; ++it) {
      int chunk = t + 256 * it;
      int row = chunk >> 3;   // n-local
      int col = chunk & 7;
      *(u16x8*)&Xt[((size_t)b * N_ + n0 + row) * C_ + c0 + col * 8] =
          *(const u16x8*)&T[row * 72 + col * 8];
    }
  } else {
    int i = (bid - 1024) * 256 + t;  // 65536 float4 chunks
    const int QCH = (3 * C_ * C_) / 4;
    const float* src =
        (i < QCH) ? wq + (size_t)i * 4 : wo + (size_t)(i - QCH) * 4;
    u16* dst = (i < QCH) ? Wqb + (size_t)i * 4 : Wob + (size_t)(i - QCH) * 4;
    f32x4 v = *(const f32x4*)src;
    u16x4 r = {f2bf(v[0]), f2bf(v[1]), f2bf(v[2]), f2bf(v[3])};
    *(u16x4*)dst = r;
  }
}

// ---------------- QKV projection, all-o-per-block ----------------
// grid (64 n0, 2 yb, 4 b); block: 64 pixels x 384 outputs; wave: 96 outputs.
// X B-frags resident (128 VGPR); per-mtile W frags from global (L2).
// Q/K mtiles: D[m=pix][n=o] -> store [n][c]; V: D[m=o][n=pix] -> store [c][n].
__global__ __launch_bounds__(256, 2) void k_qkv(
    const u16* __restrict__ Wqb, const float* __restrict__ bias,
    const u16* __restrict__ Xt, u16* __restrict__ Qt, u16* __restrict__ Kt,
    u16* __restrict__ Vn) {
  __shared__ u16 Xs[64 * 264];
  const int b = blockIdx.z, yb = blockIdx.y, n0 = blockIdx.x * 64;
  const int t = threadIdx.x, w = t >> 6, lane = t & 63;
  const int l32 = lane & 31, half = lane >> 5;
#pragma unroll
  for (int it = 0; it < 8; ++it) {
    int chunk = t + 256 * it;
    int row = chunk >> 5, col = chunk & 31;
    *(u16x8*)&Xs[row * 264 + col * 8] =
        *(const u16x8*)&Xt[((size_t)b * N_ + n0 + row) * C_ + col * 8];
  }
  __syncthreads();

  BF8 xf[2][16];
#pragma unroll
  for (int nt = 0; nt < 2; ++nt)
#pragma unroll
    for (int ks = 0; ks < 16; ++ks)
      xf[nt][ks].u =
          *(const u16x8*)&Xs[(nt * 32 + l32) * 264 + ks * 16 + half * 8];

  const int om0 = yb * 384 + w * 96;
#pragma unroll
  for (int mt = 0; mt < 3; ++mt) {
    const int om = om0 + mt * 32;
    const int seg = om >> 8;  // 0=Q 1=K 2=V
    BF8 wf[16];
    const u16* wrow = Wqb + (size_t)(om + l32) * C_ + half * 8;
#pragma unroll
    for (int ks = 0; ks < 16; ++ks) wf[ks].u = *(const u16x8*)(wrow + ks * 16);

    f32x16 a0, a1;
#pragma unroll
    for (int r = 0; r < 16; ++r) a0[r] = a1[r] = 0.f;

    if (seg < 2) {
#pragma unroll
      for (int ks = 0; ks < 16; ++ks) {
        a0 = mfma32(xf[0][ks].b, wf[ks].b, a0);
        a1 = mfma32(xf[1][ks].b, wf[ks].b, a1);
      }
      const float bvq = bias[om + l32];
      const float mult = (seg == 0) ? 0.09016844005556f : 1.0f;
      u16* dst = (seg == 0) ? Qt : Kt;
      const int ol = om & 255;
#pragma unroll
      for (int nt = 0; nt < 2; ++nt) {
        const f32x16& a = nt ? a1 : a0;
#pragma unroll
        for (int r = 0; r < 16; ++r) {
          int pix = n0 + nt * 32 + ROWMAP(r, half);
          dst[((size_t)b * N_ + pix) * C_ + ol + l32] =
              f2bf((a[r] + bvq) * mult);
        }
      }
    } else {
#pragma unroll
      for (int ks = 0; ks < 16; ++ks) {
        a0 = mfma32(wf[ks].b, xf[0][ks].b, a0);
        a1 = mfma32(wf[ks].b, xf[1][ks].b, a1);
      }
      const int ol = om & 255;
#pragma unroll
      for (int r = 0; r < 16; ++r) {
        float bv = bias[om + ROWMAP(r, half)];
        int cv = ol + ROWMAP(r, half);
#pragma unroll
        for (int nt = 0; nt < 2; ++nt) {
          int pix = n0 + nt * 32 + l32;
          const f32x16& a = nt ? a1 : a0;
          Vn[((size_t)b * C_ + cv) * N_ + pix] = f2bf(a[r] + bv);
        }
      }
    }
  }
}

// ---------------- out-proj + split-combine + bias + residual ----------------
// grid (128 n0, 4 b); block: 32 pixels x 256 outputs; wave: 64 outputs.
__global__ __launch_bounds__(256, 2) void k_out(
    const u16* __restrict__ Wob, const float* __restrict__ bias,
    const float* __restrict__ xres, float* __restrict__ outp,
    const u16* __restrict__ Op, const float* __restrict__ Ml) {
  __shared__ u16 Xs[32 * 264];
  const int b = blockIdx.y, n0 = blockIdx.x * 32;
  const int t = threadIdx.x, w = t >> 6, lane = t & 63;
  const int l32 = lane & 31, half = lane >> 5;
  const size_t TEN = (size_t)B_ * N_ * C_;
  const size_t BN = (size_t)B_ * N_;
#pragma unroll
  for (int it = 0; it < 4; ++it) {
    int chunk = t + 256 * it;
    int row = chunk >> 5, col = chunk & 31;
    size_t rowg = (size_t)b * N_ + n0 + row;
    float f = 1.0f / (Ml[rowg] + Ml[BN + rowg] + Ml[2 * BN + rowg] +
                      Ml[3 * BN + rowg]);
    size_t base = rowg * C_ + col * 8;
    u16x8 a0 = *(const u16x8*)&Op[base];
    u16x8 a1 = *(const u16x8*)&Op[TEN + base];
    u16x8 rr;
#pragma unroll
    for (int i = 0; i < 8; ++i) rr[i] = f2bf((bf2f(a0[i]) + bf2f(a1[i])) * f);
    *(u16x8*)&Xs[row * 264 + col * 8] = rr;
  }
  __syncthreads();

  BF8 xf[16];
#pragma unroll
  for (int ks = 0; ks < 16; ++ks)
    xf[ks].u = *(const u16x8*)&Xs[l32 * 264 + ks * 16 + half * 8];

#pragma unroll
  for (int mt = 0; mt < 2; ++mt) {
    const int om = w * 64 + mt * 32;
    BF8 wf[16];
    const u16* wrow = Wob + (size_t)(om + l32) * C_ + half * 8;
#pragma unroll
    for (int ks = 0; ks < 16; ++ks) wf[ks].u = *(const u16x8*)(wrow + ks * 16);
    f32x16 a;
#pragma unroll
    for (int r = 0; r < 16; ++r) a[r] = 0.f;
#pragma unroll
    for (int ks = 0; ks < 16; ++ks) a = mfma32(wf[ks].b, xf[ks].b, a);
#pragma unroll
    for (int r = 0; r < 16; ++r) {
      int oc = om + ROWMAP(r, half);
      size_t idx = ((size_t)b * C_ + oc) * N_ + n0 + l32;
      outp[idx] = a[r] + bias[oc] + xres[idx];
    }
  }
}

// ---------------- flash attention, 32x32x16 MFMA, reg-double-buffered ------
__global__ __launch_bounds__(256, 2) void k_attn(const u16* __restrict__ Qt,
                                                 const u16* __restrict__ Kt,
                                                 const u16* __restrict__ Vn,
                                                 u16* __restrict__ Op,
                                                 float* __restrict__ Ml) {
  __shared__ u16 Ks[64 * 264];   // [j][c 256 + pad]  33 KB
  __shared__ u16 Vs[256 * 72];   // [c][j 64 + pad]   36 KB
  __shared__ u16 Ps[64 * 68];    // [m][j 64 + pad]  8.5 KB
  const int id = blockIdx.x;
  const int xcd = id & 7;
  const int b = xcd >> 1;
  const int jh = xcd & 1;
  const int i0 = (id >> 3) * 64;
  const int t = threadIdx.x, w = t >> 6, lane = t & 63;
  const int l32 = lane & 31, half = lane >> 5;
  const int mh = w >> 1, jh2 = w & 1, nh = w & 1;

  BF8 qf[16];
  {
    const u16* qrow =
        Qt + ((size_t)b * N_ + i0 + mh * 32 + l32) * C_ + half * 8;
#pragma unroll
    for (int ks = 0; ks < 16; ++ks) qf[ks].u = *(const u16x8*)(qrow + ks * 16);
  }
  f32x16 o[4];
#pragma unroll
  for (int nt = 0; nt < 4; ++nt)
#pragma unroll
    for (int r = 0; r < 16; ++r) o[nt][r] = 0.f;
  float l_i = 0.f;

  const u16* kbase = Kt + (size_t)b * N_ * C_;
  const u16* vbase = Vn + (size_t)b * (size_t)C_ * N_;
  const int jbeg = jh * (N_ / 2), jend = jbeg + N_ / 2;

  const int vrow = t >> 3, vcol = (t & 7) * 8;    // V rows vrow+32*it
  const int krow = t >> 5, kcol = (t & 31) * 8;   // K rows krow+8*it
  u16x8 pv[8], pk[8];

  auto issue = [&](int j0) {
#pragma unroll
    for (int it = 0; it < 8; ++it)
      pv[it] = *(const u16x8*)&vbase[(size_t)(vrow + 32 * it) * N_ + j0 + vcol];
#pragma unroll
    for (int it = 0; it < 8; ++it)
      pk[it] = *(const u16x8*)&kbase[(size_t)(j0 + krow + 8 * it) * C_ + kcol];
  };
  auto commit = [&]() {
#pragma unroll
    for (int it = 0; it < 8; ++it)
      *(u16x8*)&Vs[(vrow + 32 * it) * 72 + vcol] = pv[it];
#pragma unroll
    for (int it = 0; it < 8; ++it)
      *(u16x8*)&Ks[(krow + 8 * it) * 264 + kcol] = pk[it];
  };

  issue(jbeg);
  commit();
  __syncthreads();

  for (int j0 = jbeg; j0 < jend; j0 += 64) {
    int jn = j0 + 64;
    if (jn >= jend) jn = jbeg;

    f32x16 s;
#pragma unroll
    for (int r = 0; r < 16; ++r) s[r] = 0.f;
#pragma unroll
    for (int ks = 0; ks < 16; ++ks) {
      BF8 kf;
      kf.u = *(const u16x8*)&Ks[(jh2 * 32 + l32) * 264 + ks * 16 + half * 8];
      s = mfma32(kf.b, qf[ks].b, s);
    }

    issue(jn);

    float tile_sum = 0.f;
#pragma unroll
    for (int g = 0; g < 4; ++g) {
      float p0 = exp2f(s[4 * g + 0]), p1 = exp2f(s[4 * g + 1]);
      float p2 = exp2f(s[4 * g + 2]), p3 = exp2f(s[4 * g + 3]);
      tile_sum += (p0 + p1) + (p2 + p3);
      u16x4 pkk = {f2bf(p0), f2bf(p1), f2bf(p2), f2bf(p3)};
      *(u16x4*)&Ps[(mh * 32 + l32) * 68 + jh2 * 32 + g * 8 + 4 * half] = pkk;
    }
    tile_sum += __shfl_xor(tile_sum, 32);
    l_i += tile_sum;

    __syncthreads();

    BF8 pf[4];
#pragma unroll
    for (int ks = 0; ks < 4; ++ks)
      pf[ks].u = *(const u16x8*)&Ps[(mh * 32 + l32) * 68 + ks * 16 + half * 8];
#pragma unroll
    for (int nt = 0; nt < 4; ++nt) {
#pragma unroll
      for (int ks = 0; ks < 4; ++ks) {
        BF8 vf;
        vf.u = *(const u16x8*)&Vs[(nh * 128 + nt * 32 + l32) * 72 + ks * 16 +
                                  half * 8];
        o[nt] = mfma32(pf[ks].b, vf.b, o[nt]);
      }
    }

    __syncthreads();
    commit();
    __syncthreads();
  }

  u16* op = Op + ((size_t)jh * B_ + b) * (size_t)N_ * C_;
  float* ml = Ml + ((size_t)(jh * 2 + jh2) * B_ + b) * N_;
  if (lane < 32) ml[i0 + mh * 32 + l32] = l_i;
#pragma unroll
  for (int nt = 0; nt < 4; ++nt)
#pragma unroll
    for (int r = 0; r < 16; ++r) {
      int qrow = i0 + mh * 32 + ROWMAP(r, half);
      op[(size_t)qrow * C_ + nh * 128 + nt * 32 + l32] = f2bf(o[nt][r]);
    }
}

extern "C" void kernel_launch(void* const* d_in, const int* in_sizes, int n_in,
                              void* d_out, int out_size, void* d_ws,
                              size_t ws_size, hipStream_t stream) {
  (void)in_sizes; (void)n_in; (void)out_size; (void)ws_size;
  const float* x = (const float*)d_in[0];
  const float* w_qkv = (const float*)d_in[1];
  const float* b_qkv = (const float*)d_in[2];
  const float* w_out = (const float*)d_in[3];
  const float* b_out = (const float*)d_in[4];
  float* outp = (float*)d_out;

  const size_t TENS = (size_t)B_ * N_ * C_;  // 4M elems
  u16* Xt = (u16*)d_ws;      // [B][N][C] bf16              8 MB
  u16* Qt = Xt + TENS;       // [B][N][C] bf16 (scaled)     8 MB
  u16* Kt = Qt + TENS;       // [B][N][C] bf16              8 MB
  u16* Vn = Kt + TENS;       // [B][C][N] bf16              8 MB
  u16* Op = Vn + TENS;       // [2][B][N][C] bf16          16 MB
  float* Ml = (float*)(Op + 2 * TENS);          // [4][B][N]  256 KB
  u16* Wqb = (u16*)(Ml + 4 * (size_t)B_ * N_);  // [3C][C]    384 KB
  u16* Wob = Wqb + 3 * C_ * C_;                 // [C][C]     128 KB

  k_pre<<<dim3(1280), 256, 0, stream>>>(x, Xt, w_qkv, w_out, Wqb, Wob);
  k_qkv<<<dim3(64, 2, 4), 256, 0, stream>>>(Wqb, b_qkv, Xt, Qt, Kt, Vn);
  k_attn<<<dim3(512), 256, 0, stream>>>(Qt, Kt, Vn, Op, Ml);
  k_out<<<dim3(128, 4), 256, 0, stream>>>(Wob, b_out, x, outp, Op, Ml);
}

// Round 7
// 220.008 us; speedup vs baseline: 1.7895x; 1.0047x over previous
//
#include <hip/hip_runtime.h>

#define B_ 4
#define C_ 256
#define N_ 4096

typedef unsigned short u16;
typedef __bf16 bf16x8 __attribute__((ext_vector_type(8)));
typedef float f32x4 __attribute__((ext_vector_type(4)));
typedef float f32x16 __attribute__((ext_vector_type(16)));
typedef u16 u16x8 __attribute__((ext_vector_type(8)));
typedef u16 u16x4 __attribute__((ext_vector_type(4)));

union BF8 { u16x8 u; bf16x8 b; };

__device__ __forceinline__ u16 f2bf(float f) {  // RNE (cold paths)
  unsigned int u = __float_as_uint(f);
  u += 0x7fffu + ((u >> 16) & 1u);
  return (u16)(u >> 16);
}
__device__ __forceinline__ u16 f2bf_fast(float f) {  // round-half-up, 2 ops
  return (u16)((__float_as_uint(f) + 0x8000u) >> 16);
}
__device__ __forceinline__ float bf2f(u16 u) {
  return __uint_as_float(((unsigned int)u) << 16);
}

__device__ __forceinline__ f32x16 mfma32(bf16x8 a, bf16x8 b, f32x16 c) {
  return __builtin_amdgcn_mfma_f32_32x32x16_bf16(a, b, c, 0, 0, 0);
}

#define ROWMAP(r, half) (((r) & 3) + 8 * ((r) >> 2) + 4 * (half))

// ---------------- weights fp32 -> bf16 (once, tiny) ----------------
__global__ __launch_bounds__(256) void k_prep(const float* __restrict__ wq,
                                              const float* __restrict__ wo,
                                              u16* __restrict__ Wqb,
                                              u16* __restrict__ Wob) {
  int i = blockIdx.x * 256 + threadIdx.x;  // 65536 float4 chunks
  const int QCH = (3 * C_ * C_) / 4;
  const float* src = (i < QCH) ? wq + (size_t)i * 4 : wo + (size_t)(i - QCH) * 4;
  u16* dst = (i < QCH) ? Wqb + (size_t)i * 4 : Wob + (size_t)(i - QCH) * 4;
  f32x4 v = *(const f32x4*)src;
  u16x4 r = {f2bf(v[0]), f2bf(v[1]), f2bf(v[2]), f2bf(v[3])};
  *(u16x4*)dst = r;
}

// ---------------- QKV projection with fused x-transpose ----------------
// grid (64 n0, 2 yb, 4 b); block: 64 pixels x 384 outputs; wave: 96 outputs.
// Stage x[b][:, n0:n0+64] fp32 -> LDS [64 n][264 c] bf16 (transpose+cvt),
// X B-frags resident (128 VGPR); per-mtile W frags from global (L2).
// Q/K mtiles: D[m=pix][n=o] -> store [n][c]; V: D[m=o][n=pix] -> store [c][n].
__global__ __launch_bounds__(256, 2) void k_qkv(
    const u16* __restrict__ Wqb, const float* __restrict__ bias,
    const float* __restrict__ x, u16* __restrict__ Qt, u16* __restrict__ Kt,
    u16* __restrict__ Vn) {
  __shared__ u16 Xs[64 * 264];
  const int b = blockIdx.z, yb = blockIdx.y, n0 = blockIdx.x * 64;
  const int t = threadIdx.x, w = t >> 6, lane = t & 63;
  const int l32 = lane & 31, half = lane >> 5;
#pragma unroll
  for (int it = 0; it < 16; ++it) {
    int chunk = t + 256 * it;
    int row = chunk >> 4;   // c 0..255
    int col = chunk & 15;   // float4 along n
    f32x4 v = *(const f32x4*)(x + (((size_t)b * C_ + row) * N_ + n0 + col * 4));
#pragma unroll
    for (int i = 0; i < 4; ++i) Xs[(col * 4 + i) * 264 + row] = f2bf(v[i]);
  }
  __syncthreads();

  BF8 xf[2][16];
#pragma unroll
  for (int nt = 0; nt < 2; ++nt)
#pragma unroll
    for (int ks = 0; ks < 16; ++ks)
      xf[nt][ks].u =
          *(const u16x8*)&Xs[(nt * 32 + l32) * 264 + ks * 16 + half * 8];

  const int om0 = yb * 384 + w * 96;
#pragma unroll
  for (int mt = 0; mt < 3; ++mt) {
    const int om = om0 + mt * 32;
    const int seg = om >> 8;  // 0=Q 1=K 2=V
    BF8 wf[16];
    const u16* wrow = Wqb + (size_t)(om + l32) * C_ + half * 8;
#pragma unroll
    for (int ks = 0; ks < 16; ++ks) wf[ks].u = *(const u16x8*)(wrow + ks * 16);

    f32x16 a0, a1;
#pragma unroll
    for (int r = 0; r < 16; ++r) a0[r] = a1[r] = 0.f;

    if (seg < 2) {
#pragma unroll
      for (int ks = 0; ks < 16; ++ks) {
        a0 = mfma32(xf[0][ks].b, wf[ks].b, a0);
        a1 = mfma32(xf[1][ks].b, wf[ks].b, a1);
      }
      const float bvq = bias[om + l32];
      const float mult = (seg == 0) ? 0.09016844005556f : 1.0f;
      u16* dst = (seg == 0) ? Qt : Kt;
      const int ol = om & 255;
#pragma unroll
      for (int nt = 0; nt < 2; ++nt) {
        const f32x16& a = nt ? a1 : a0;
#pragma unroll
        for (int r = 0; r < 16; ++r) {
          int pix = n0 + nt * 32 + ROWMAP(r, half);
          dst[((size_t)b * N_ + pix) * C_ + ol + l32] =
              f2bf((a[r] + bvq) * mult);
        }
      }
    } else {
#pragma unroll
      for (int ks = 0; ks < 16; ++ks) {
        a0 = mfma32(wf[ks].b, xf[0][ks].b, a0);
        a1 = mfma32(wf[ks].b, xf[1][ks].b, a1);
      }
      const int ol = om & 255;
#pragma unroll
      for (int r = 0; r < 16; ++r) {
        float bv = bias[om + ROWMAP(r, half)];
        int cv = ol + ROWMAP(r, half);
#pragma unroll
        for (int nt = 0; nt < 2; ++nt) {
          int pix = n0 + nt * 32 + l32;
          const f32x16& a = nt ? a1 : a0;
          Vn[((size_t)b * C_ + cv) * N_ + pix] = f2bf(a[r] + bv);
        }
      }
    }
  }
}

// ---------------- out-proj + split-combine + bias + residual ----------------
// grid (128 n0, 4 b); block: 32 pixels x 256 outputs; wave: 64 outputs.
__global__ __launch_bounds__(256, 2) void k_out(
    const u16* __restrict__ Wob, const float* __restrict__ bias,
    const float* __restrict__ xres, float* __restrict__ outp,
    const u16* __restrict__ Op, const float* __restrict__ Ml) {
  __shared__ u16 Xs[32 * 264];
  const int b = blockIdx.y, n0 = blockIdx.x * 32;
  const int t = threadIdx.x, w = t >> 6, lane = t & 63;
  const int l32 = lane & 31, half = lane >> 5;
  const size_t TEN = (size_t)B_ * N_ * C_;
  const size_t BN = (size_t)B_ * N_;
#pragma unroll
  for (int it = 0; it < 4; ++it) {
    int chunk = t + 256 * it;
    int row = chunk >> 5, col = chunk & 31;
    size_t rowg = (size_t)b * N_ + n0 + row;
    float f = 1.0f / (Ml[rowg] + Ml[BN + rowg] + Ml[2 * BN + rowg] +
                      Ml[3 * BN + rowg]);
    size_t base = rowg * C_ + col * 8;
    u16x8 a0 = *(const u16x8*)&Op[base];
    u16x8 a1 = *(const u16x8*)&Op[TEN + base];
    u16x8 rr;
#pragma unroll
    for (int i = 0; i < 8; ++i) rr[i] = f2bf((bf2f(a0[i]) + bf2f(a1[i])) * f);
    *(u16x8*)&Xs[row * 264 + col * 8] = rr;
  }
  __syncthreads();

  BF8 xf[16];
#pragma unroll
  for (int ks = 0; ks < 16; ++ks)
    xf[ks].u = *(const u16x8*)&Xs[l32 * 264 + ks * 16 + half * 8];

#pragma unroll
  for (int mt = 0; mt < 2; ++mt) {
    const int om = w * 64 + mt * 32;
    BF8 wf[16];
    const u16* wrow = Wob + (size_t)(om + l32) * C_ + half * 8;
#pragma unroll
    for (int ks = 0; ks < 16; ++ks) wf[ks].u = *(const u16x8*)(wrow + ks * 16);
    f32x16 a;
#pragma unroll
    for (int r = 0; r < 16; ++r) a[r] = 0.f;
#pragma unroll
    for (int ks = 0; ks < 16; ++ks) a = mfma32(wf[ks].b, xf[ks].b, a);
#pragma unroll
    for (int r = 0; r < 16; ++r) {
      int oc = om + ROWMAP(r, half);
      size_t idx = ((size_t)b * C_ + oc) * N_ + n0 + l32;
      outp[idx] = a[r] + bias[oc] + xres[idx];
    }
  }
}

// ---------------- flash attention, 32x32x16 MFMA, reg-double-buffered ------
__global__ __launch_bounds__(256, 2) void k_attn(const u16* __restrict__ Qt,
                                                 const u16* __restrict__ Kt,
                                                 const u16* __restrict__ Vn,
                                                 u16* __restrict__ Op,
                                                 float* __restrict__ Ml) {
  __shared__ u16 Ks[64 * 264];   // [j][c 256 + pad]  33 KB
  __shared__ u16 Vs[256 * 72];   // [c][j 64 + pad]   36 KB
  __shared__ u16 Ps[64 * 68];    // [m][j 64 + pad]  8.5 KB
  const int id = blockIdx.x;
  const int xcd = id & 7;
  const int b = xcd >> 1;
  const int jh = xcd & 1;
  const int i0 = (id >> 3) * 64;
  const int t = threadIdx.x, w = t >> 6, lane = t & 63;
  const int l32 = lane & 31, half = lane >> 5;
  const int mh = w >> 1, jh2 = w & 1, nh = w & 1;

  BF8 qf[16];
  {
    const u16* qrow =
        Qt + ((size_t)b * N_ + i0 + mh * 32 + l32) * C_ + half * 8;
#pragma unroll
    for (int ks = 0; ks < 16; ++ks) qf[ks].u = *(const u16x8*)(qrow + ks * 16);
  }
  f32x16 o[4];
#pragma unroll
  for (int nt = 0; nt < 4; ++nt)
#pragma unroll
    for (int r = 0; r < 16; ++r) o[nt][r] = 0.f;
  float l_i = 0.f;

  const u16* kbase = Kt + (size_t)b * N_ * C_;
  const u16* vbase = Vn + (size_t)b * (size_t)C_ * N_;
  const int jbeg = jh * (N_ / 2), jend = jbeg + N_ / 2;

  const int vrow = t >> 3, vcol = (t & 7) * 8;    // V rows vrow+32*it
  const int krow = t >> 5, kcol = (t & 31) * 8;   // K rows krow+8*it
  u16x8 pv[8], pk[8];

  auto issue = [&](int j0) {
#pragma unroll
    for (int it = 0; it < 8; ++it)
      pv[it] = *(const u16x8*)&vbase[(size_t)(vrow + 32 * it) * N_ + j0 + vcol];
#pragma unroll
    for (int it = 0; it < 8; ++it)
      pk[it] = *(const u16x8*)&kbase[(size_t)(j0 + krow + 8 * it) * C_ + kcol];
  };
  auto commit = [&]() {
#pragma unroll
    for (int it = 0; it < 8; ++it)
      *(u16x8*)&Vs[(vrow + 32 * it) * 72 + vcol] = pv[it];
#pragma unroll
    for (int it = 0; it < 8; ++it)
      *(u16x8*)&Ks[(krow + 8 * it) * 264 + kcol] = pk[it];
  };

  issue(jbeg);
  commit();
  __syncthreads();

  for (int j0 = jbeg; j0 < jend; j0 += 64) {
    int jn = j0 + 64;
    if (jn >= jend) jn = jbeg;
    issue(jn);  // prefetch early: hides behind QK MFMA + exp + PV

    f32x16 s;
#pragma unroll
    for (int r = 0; r < 16; ++r) s[r] = 0.f;
#pragma unroll
    for (int ks = 0; ks < 16; ++ks) {
      BF8 kf;
      kf.u = *(const u16x8*)&Ks[(jh2 * 32 + l32) * 264 + ks * 16 + half * 8];
      s = mfma32(kf.b, qf[ks].b, s);
    }

    float tile_sum = 0.f;
#pragma unroll
    for (int g = 0; g < 4; ++g) {
      float p0 = exp2f(s[4 * g + 0]), p1 = exp2f(s[4 * g + 1]);
      float p2 = exp2f(s[4 * g + 2]), p3 = exp2f(s[4 * g + 3]);
      tile_sum += (p0 + p1) + (p2 + p3);
      u16x4 pkk = {f2bf_fast(p0), f2bf_fast(p1), f2bf_fast(p2), f2bf_fast(p3)};
      *(u16x4*)&Ps[(mh * 32 + l32) * 68 + jh2 * 32 + g * 8 + 4 * half] = pkk;
    }
    tile_sum += __shfl_xor(tile_sum, 32);
    l_i += tile_sum;

    __syncthreads();

    BF8 pf[4];
#pragma unroll
    for (int ks = 0; ks < 4; ++ks)
      pf[ks].u = *(const u16x8*)&Ps[(mh * 32 + l32) * 68 + ks * 16 + half * 8];
#pragma unroll
    for (int nt = 0; nt < 4; ++nt) {
#pragma unroll
      for (int ks = 0; ks < 4; ++ks) {
        BF8 vf;
        vf.u = *(const u16x8*)&Vs[(nh * 128 + nt * 32 + l32) * 72 + ks * 16 +
                                  half * 8];
        o[nt] = mfma32(pf[ks].b, vf.b, o[nt]);
      }
    }

    __syncthreads();
    commit();
    __syncthreads();
  }

  u16* op = Op + ((size_t)jh * B_ + b) * (size_t)N_ * C_;
  float* ml = Ml + ((size_t)(jh * 2 + jh2) * B_ + b) * N_;
  if (lane < 32) ml[i0 + mh * 32 + l32] = l_i;
#pragma unroll
  for (int nt = 0; nt < 4; ++nt)
#pragma unroll
    for (int r = 0; r < 16; ++r) {
      int qrow = i0 + mh * 32 + ROWMAP(r, half);
      op[(size_t)qrow * C_ + nh * 128 + nt * 32 + l32] = f2bf_fast(o[nt][r]);
    }
}

extern "C" void kernel_launch(void* const* d_in, const int* in_sizes, int n_in,
                              void* d_out, int out_size, void* d_ws,
                              size_t ws_size, hipStream_t stream) {
  (void)in_sizes; (void)n_in; (void)out_size; (void)ws_size;
  const float* x = (const float*)d_in[0];
  const float* w_qkv = (const float*)d_in[1];
  const float* b_qkv = (const float*)d_in[2];
  const float* w_out = (const float*)d_in[3];
  const float* b_out = (const float*)d_in[4];
  float* outp = (float*)d_out;

  const size_t TENS = (size_t)B_ * N_ * C_;  // 4M elems
  u16* Qt = (u16*)d_ws;      // [B][N][C] bf16 (scaled)     8 MB
  u16* Kt = Qt + TENS;       // [B][N][C] bf16              8 MB
  u16* Vn = Kt + TENS;       // [B][C][N] bf16              8 MB
  u16* Op = Vn + TENS;       // [2][B][N][C] bf16          16 MB
  float* Ml = (float*)(Op + 2 * TENS);          // [4][B][N]  256 KB
  u16* Wqb = (u16*)(Ml + 4 * (size_t)B_ * N_);  // [3C][C]    384 KB
  u16* Wob = Wqb + 3 * C_ * C_;                 // [C][C]     128 KB

  k_prep<<<dim3(256), 256, 0, stream>>>(w_qkv, w_out, Wqb, Wob);
  k_qkv<<<dim3(64, 2, 4), 256, 0, stream>>>(Wqb, b_qkv, x, Qt, Kt, Vn);
  k_attn<<<dim3(512), 256, 0, stream>>>(Qt, Kt, Vn, Op, Ml);
  k_out<<<dim3(128, 4), 256, 0, stream>>>(Wob, b_out, x, outp, Op, Ml);
}

// Round 8
// 193.560 us; speedup vs baseline: 2.0341x; 1.1366x over previous
//
#include <hip/hip_runtime.h>

#define B_ 4
#define C_ 256
#define N_ 4096

typedef unsigned short u16;
typedef unsigned char u8;
typedef __bf16 bf16x8 __attribute__((ext_vector_type(8)));
typedef float f32x4 __attribute__((ext_vector_type(4)));
typedef float f32x16 __attribute__((ext_vector_type(16)));
typedef u16 u16x8 __attribute__((ext_vector_type(8)));
typedef u16 u16x4 __attribute__((ext_vector_type(4)));
typedef u8 u8x16 __attribute__((ext_vector_type(16)));

union BF8 { u16x8 u; bf16x8 b; };
union PK16 { u8x16 v; long l[2]; };

__device__ __forceinline__ u16 f2bf(float f) {  // RNE
  unsigned int u = __float_as_uint(f);
  u += 0x7fffu + ((u >> 16) & 1u);
  return (u16)(u >> 16);
}
__device__ __forceinline__ u16 f2bf_fast(float f) {  // round-half-up
  return (u16)((__float_as_uint(f) + 0x8000u) >> 16);
}
__device__ __forceinline__ float bf2f(u16 u) {
  return __uint_as_float(((unsigned int)u) << 16);
}
__device__ __forceinline__ u8 f2fp8(float v) {  // OCP e4m3 on gfx950
  return (u8)__builtin_amdgcn_cvt_pk_fp8_f32(v, v, 0, false);
}

__device__ __forceinline__ f32x16 mfma32(bf16x8 a, bf16x8 b, f32x16 c) {
  return __builtin_amdgcn_mfma_f32_32x32x16_bf16(a, b, c, 0, 0, 0);
}
__device__ __forceinline__ f32x16 mfma32f8(long a, long b, f32x16 c) {
  return __builtin_amdgcn_mfma_f32_32x32x16_fp8_fp8(a, b, c, 0, 0, 0);
}

#define ROWMAP(r, half) (((r) & 3) + 8 * ((r) >> 2) + 4 * (half))

// sqrt((1/16)*log2e): folded into BOTH q and k so softmax is bare exp2,
// and fp8 values sit in e4m3 normal range (sigma ~0.18).
#define QK_SCALE 0.30028063f

// ---------------- weights fp32 -> bf16 (once, tiny) ----------------
__global__ __launch_bounds__(256) void k_prep(const float* __restrict__ wq,
                                              const float* __restrict__ wo,
                                              u16* __restrict__ Wqb,
                                              u16* __restrict__ Wob) {
  int i = blockIdx.x * 256 + threadIdx.x;  // 65536 float4 chunks
  const int QCH = (3 * C_ * C_) / 4;
  const float* src = (i < QCH) ? wq + (size_t)i * 4 : wo + (size_t)(i - QCH) * 4;
  u16* dst = (i < QCH) ? Wqb + (size_t)i * 4 : Wob + (size_t)(i - QCH) * 4;
  f32x4 v = *(const f32x4*)src;
  u16x4 r = {f2bf(v[0]), f2bf(v[1]), f2bf(v[2]), f2bf(v[3])};
  *(u16x4*)dst = r;
}

// ---------------- QKV projection (bf16 GEMM) -> fp8 Q/K/V ----------------
// grid (64 n0, 2 yb, 4 b); block: 64 pixels x 384 outputs; wave: 96 outputs.
__global__ __launch_bounds__(256, 2) void k_qkv(
    const u16* __restrict__ Wqb, const float* __restrict__ bias,
    const float* __restrict__ x, u8* __restrict__ Qt, u8* __restrict__ Kt,
    u8* __restrict__ Vn) {
  __shared__ u16 Xs[64 * 264];
  const int b = blockIdx.z, yb = blockIdx.y, n0 = blockIdx.x * 64;
  const int t = threadIdx.x, w = t >> 6, lane = t & 63;
  const int l32 = lane & 31, half = lane >> 5;
#pragma unroll
  for (int it = 0; it < 16; ++it) {
    int chunk = t + 256 * it;
    int row = chunk >> 4;   // c 0..255
    int col = chunk & 15;   // float4 along n
    f32x4 v = *(const f32x4*)(x + (((size_t)b * C_ + row) * N_ + n0 + col * 4));
#pragma unroll
    for (int i = 0; i < 4; ++i) Xs[(col * 4 + i) * 264 + row] = f2bf(v[i]);
  }
  __syncthreads();

  BF8 xf[2][16];
#pragma unroll
  for (int nt = 0; nt < 2; ++nt)
#pragma unroll
    for (int ks = 0; ks < 16; ++ks)
      xf[nt][ks].u =
          *(const u16x8*)&Xs[(nt * 32 + l32) * 264 + ks * 16 + half * 8];

  const int om0 = yb * 384 + w * 96;
#pragma unroll
  for (int mt = 0; mt < 3; ++mt) {
    const int om = om0 + mt * 32;
    const int seg = om >> 8;  // 0=Q 1=K 2=V
    BF8 wf[16];
    const u16* wrow = Wqb + (size_t)(om + l32) * C_ + half * 8;
#pragma unroll
    for (int ks = 0; ks < 16; ++ks) wf[ks].u = *(const u16x8*)(wrow + ks * 16);

    f32x16 a0, a1;
#pragma unroll
    for (int r = 0; r < 16; ++r) a0[r] = a1[r] = 0.f;

    if (seg < 2) {
#pragma unroll
      for (int ks = 0; ks < 16; ++ks) {
        a0 = mfma32(xf[0][ks].b, wf[ks].b, a0);
        a1 = mfma32(xf[1][ks].b, wf[ks].b, a1);
      }
      const float bvq = bias[om + l32];
      u8* dst = (seg == 0) ? Qt : Kt;
      const int ol = om & 255;
#pragma unroll
      for (int nt = 0; nt < 2; ++nt) {
        const f32x16& a = nt ? a1 : a0;
#pragma unroll
        for (int r = 0; r < 16; ++r) {
          int pix = n0 + nt * 32 + ROWMAP(r, half);
          dst[((size_t)b * N_ + pix) * C_ + ol + l32] =
              f2fp8((a[r] + bvq) * QK_SCALE);
        }
      }
    } else {
#pragma unroll
      for (int ks = 0; ks < 16; ++ks) {
        a0 = mfma32(wf[ks].b, xf[0][ks].b, a0);
        a1 = mfma32(wf[ks].b, xf[1][ks].b, a1);
      }
      const int ol = om & 255;
#pragma unroll
      for (int r = 0; r < 16; ++r) {
        float bv = bias[om + ROWMAP(r, half)];
        int cv = ol + ROWMAP(r, half);
#pragma unroll
        for (int nt = 0; nt < 2; ++nt) {
          int pix = n0 + nt * 32 + l32;
          const f32x16& a = nt ? a1 : a0;
          Vn[((size_t)b * C_ + cv) * N_ + pix] = f2fp8(a[r] + bv);
        }
      }
    }
  }
}

// ---------------- out-proj + split-combine + bias + residual ----------------
__global__ __launch_bounds__(256, 2) void k_out(
    const u16* __restrict__ Wob, const float* __restrict__ bias,
    const float* __restrict__ xres, float* __restrict__ outp,
    const u16* __restrict__ Op, const float* __restrict__ Ml) {
  __shared__ u16 Xs[32 * 264];
  const int b = blockIdx.y, n0 = blockIdx.x * 32;
  const int t = threadIdx.x, w = t >> 6, lane = t & 63;
  const int l32 = lane & 31, half = lane >> 5;
  const size_t TEN = (size_t)B_ * N_ * C_;
  const size_t BN = (size_t)B_ * N_;
#pragma unroll
  for (int it = 0; it < 4; ++it) {
    int chunk = t + 256 * it;
    int row = chunk >> 5, col = chunk & 31;
    size_t rowg = (size_t)b * N_ + n0 + row;
    float f = 1.0f / (Ml[rowg] + Ml[BN + rowg] + Ml[2 * BN + rowg] +
                      Ml[3 * BN + rowg]);
    size_t base = rowg * C_ + col * 8;
    u16x8 a0 = *(const u16x8*)&Op[base];
    u16x8 a1 = *(const u16x8*)&Op[TEN + base];
    u16x8 rr;
#pragma unroll
    for (int i = 0; i < 8; ++i) rr[i] = f2bf((bf2f(a0[i]) + bf2f(a1[i])) * f);
    *(u16x8*)&Xs[row * 264 + col * 8] = rr;
  }
  __syncthreads();

  BF8 xf[16];
#pragma unroll
  for (int ks = 0; ks < 16; ++ks)
    xf[ks].u = *(const u16x8*)&Xs[l32 * 264 + ks * 16 + half * 8];

#pragma unroll
  for (int mt = 0; mt < 2; ++mt) {
    const int om = w * 64 + mt * 32;
    BF8 wf[16];
    const u16* wrow = Wob + (size_t)(om + l32) * C_ + half * 8;
#pragma unroll
    for (int ks = 0; ks < 16; ++ks) wf[ks].u = *(const u16x8*)(wrow + ks * 16);
    f32x16 a;
#pragma unroll
    for (int r = 0; r < 16; ++r) a[r] = 0.f;
#pragma unroll
    for (int ks = 0; ks < 16; ++ks) a = mfma32(wf[ks].b, xf[ks].b, a);
#pragma unroll
    for (int r = 0; r < 16; ++r) {
      int oc = om + ROWMAP(r, half);
      size_t idx = ((size_t)b * C_ + oc) * N_ + n0 + l32;
      outp[idx] = a[r] + bias[oc] + xres[idx];
    }
  }
}

// ---------------- flash attention, fp8 MFMA, LDS-double-buffered ------------
// grid: 512 blocks. xcd = id&7 -> b = xcd>>1, jhalf = xcd&1 (XCD-local KV).
// fp8 e4m3 Q/K/V/P at bf16 MFMA rate, half the LDS/staging bytes.
// K/V tiles double-buffered: commit targets idle buffer -> 2 barriers/iter.
__global__ __launch_bounds__(256, 2) void k_attn(const u8* __restrict__ Qt,
                                                 const u8* __restrict__ Kt,
                                                 const u8* __restrict__ Vn,
                                                 u16* __restrict__ Op,
                                                 float* __restrict__ Ml) {
  __shared__ u8 Ks[2][64 * 264];   // [j][c 256 + pad8]   2x16.5 KB
  __shared__ u8 Vs[2][256 * 72];   // [c][j 64 + pad8]    2x18 KB
  __shared__ u8 Ps[64 * 72];       // [m][j 64 + pad8]    4.5 KB (total 73.5)
  const int id = blockIdx.x;
  const int xcd = id & 7;
  const int b = xcd >> 1;
  const int jh = xcd & 1;
  const int i0 = (id >> 3) * 64;
  const int t = threadIdx.x, w = t >> 6, lane = t & 63;
  const int l32 = lane & 31, half = lane >> 5;
  const int mh = w >> 1, jh2 = w & 1, nh = w & 1;

  long qf[16];
  {
    const u8* qrow = Qt + ((size_t)b * N_ + i0 + mh * 32 + l32) * C_ + half * 8;
#pragma unroll
    for (int ks = 0; ks < 16; ++ks) qf[ks] = *(const long*)(qrow + ks * 16);
  }
  f32x16 o[4];
#pragma unroll
  for (int nt = 0; nt < 4; ++nt)
#pragma unroll
    for (int r = 0; r < 16; ++r) o[nt][r] = 0.f;
  float l_i = 0.f;

  const u8* kbase = Kt + (size_t)b * N_ * C_;
  const u8* vbase = Vn + (size_t)b * (size_t)C_ * N_;
  const int jbeg = jh * (N_ / 2), jend = jbeg + N_ / 2;

  const int krow = t >> 4, kcol = (t & 15) * 16;  // K rows krow+16*it
  const int vrow = t >> 2, vcol = (t & 3) * 16;   // V rows vrow+64*it
  PK16 pk[4], pv[4];  // 32 VGPRs of prefetch

  auto issue = [&](int j0) {
#pragma unroll
    for (int it = 0; it < 4; ++it)
      pv[it].v =
          *(const u8x16*)&vbase[(size_t)(vrow + 64 * it) * N_ + j0 + vcol];
#pragma unroll
    for (int it = 0; it < 4; ++it)
      pk[it].v =
          *(const u8x16*)&kbase[(size_t)(j0 + krow + 16 * it) * C_ + kcol];
  };
  auto commit = [&](int buf) {
#pragma unroll
    for (int it = 0; it < 4; ++it) {
      u8* p = &Vs[buf][(vrow + 64 * it) * 72 + vcol];
      *(long*)p = pv[it].l[0];
      *(long*)(p + 8) = pv[it].l[1];
    }
#pragma unroll
    for (int it = 0; it < 4; ++it) {
      u8* p = &Ks[buf][(krow + 16 * it) * 264 + kcol];
      *(long*)p = pk[it].l[0];
      *(long*)(p + 8) = pk[it].l[1];
    }
  };

  issue(jbeg);
  commit(0);
  __syncthreads();
  int cur = 0;

  for (int j0 = jbeg; j0 < jend; j0 += 64) {
    int jn = j0 + 64;
    if (jn >= jend) jn = jbeg;  // last iter: dummy (valid) prefetch
    issue(jn);

    // S^T 32x32: rows j (16 regs), cols m = l32
    f32x16 s;
#pragma unroll
    for (int r = 0; r < 16; ++r) s[r] = 0.f;
#pragma unroll
    for (int ks = 0; ks < 16; ++ks) {
      long kf =
          *(const long*)&Ks[cur][(jh2 * 32 + l32) * 264 + ks * 16 + half * 8];
      s = mfma32f8(kf, qf[ks], s);
    }

    // p = exp2(s); pack 4 fp8 per dword into Ps; in-lane sum
    float tile_sum = 0.f;
#pragma unroll
    for (int g = 0; g < 4; ++g) {
      float p0 = exp2f(s[4 * g + 0]), p1 = exp2f(s[4 * g + 1]);
      float p2 = exp2f(s[4 * g + 2]), p3 = exp2f(s[4 * g + 3]);
      tile_sum += (p0 + p1) + (p2 + p3);
      int w0 = __builtin_amdgcn_cvt_pk_fp8_f32(p0, p1, 0, false);
      w0 = __builtin_amdgcn_cvt_pk_fp8_f32(p2, p3, w0, true);
      *(int*)&Ps[(mh * 32 + l32) * 72 + jh2 * 32 + g * 8 + 4 * half] = w0;
    }
    tile_sum += __shfl_xor(tile_sum, 32);
    l_i += tile_sum;

    __syncthreads();  // Ps visible

    long pf[4];
#pragma unroll
    for (int kc = 0; kc < 4; ++kc)
      pf[kc] = *(const long*)&Ps[(mh * 32 + l32) * 72 + kc * 16 + half * 8];
#pragma unroll
    for (int nt = 0; nt < 4; ++nt) {
#pragma unroll
      for (int kc = 0; kc < 4; ++kc) {
        long vf = *(const long*)&Vs[cur][(nh * 128 + nt * 32 + l32) * 72 +
                                         kc * 16 + half * 8];
        o[nt] = mfma32f8(pf[kc], vf, o[nt]);
      }
    }

    commit(cur ^ 1);  // idle buffer: no read conflict
    __syncthreads();  // commit + Ps reads done before next iter
    cur ^= 1;
  }

  u16* op = Op + ((size_t)jh * B_ + b) * (size_t)N_ * C_;
  float* ml = Ml + ((size_t)(jh * 2 + jh2) * B_ + b) * N_;
  if (lane < 32) ml[i0 + mh * 32 + l32] = l_i;
#pragma unroll
  for (int nt = 0; nt < 4; ++nt)
#pragma unroll
    for (int r = 0; r < 16; ++r) {
      int qrow = i0 + mh * 32 + ROWMAP(r, half);
      op[(size_t)qrow * C_ + nh * 128 + nt * 32 + l32] = f2bf_fast(o[nt][r]);
    }
}

extern "C" void kernel_launch(void* const* d_in, const int* in_sizes, int n_in,
                              void* d_out, int out_size, void* d_ws,
                              size_t ws_size, hipStream_t stream) {
  (void)in_sizes; (void)n_in; (void)out_size; (void)ws_size;
  const float* x = (const float*)d_in[0];
  const float* w_qkv = (const float*)d_in[1];
  const float* b_qkv = (const float*)d_in[2];
  const float* w_out = (const float*)d_in[3];
  const float* b_out = (const float*)d_in[4];
  float* outp = (float*)d_out;

  const size_t TENS = (size_t)B_ * N_ * C_;  // 4M elems
  u8* Qt = (u8*)d_ws;        // [B][N][C] fp8 (scaled)      4 MB
  u8* Kt = Qt + TENS;        // [B][N][C] fp8 (scaled)      4 MB
  u8* Vn = Kt + TENS;        // [B][C][N] fp8               4 MB
  u16* Op = (u16*)(Vn + TENS);  // [2][B][N][C] bf16       16 MB
  float* Ml = (float*)(Op + 2 * TENS);          // [4][B][N]  256 KB
  u16* Wqb = (u16*)(Ml + 4 * (size_t)B_ * N_);  // [3C][C]    384 KB
  u16* Wob = Wqb + 3 * C_ * C_;                 // [C][C]     128 KB

  k_prep<<<dim3(256), 256, 0, stream>>>(w_qkv, w_out, Wqb, Wob);
  k_qkv<<<dim3(64, 2, 4), 256, 0, stream>>>(Wqb, b_qkv, x, Qt, Kt, Vn);
  k_attn<<<dim3(512), 256, 0, stream>>>(Qt, Kt, Vn, Op, Ml);
  k_out<<<dim3(128, 4), 256, 0, stream>>>(Wob, b_out, x, outp, Op, Ml);
}

// Round 10
// 173.828 us; speedup vs baseline: 2.2650x; 1.1135x over previous
//
#include <hip/hip_runtime.h>

#define B_ 4
#define C_ 256
#define N_ 4096

typedef unsigned short u16;
typedef unsigned char u8;
typedef __bf16 bf16x8 __attribute__((ext_vector_type(8)));
typedef float f32x4 __attribute__((ext_vector_type(4)));
typedef float f32x16 __attribute__((ext_vector_type(16)));
typedef u16 u16x8 __attribute__((ext_vector_type(8)));
typedef u16 u16x4 __attribute__((ext_vector_type(4)));
typedef u8 u8x16 __attribute__((ext_vector_type(16)));

union BF8 { u16x8 u; bf16x8 b; };

__device__ __forceinline__ u16 f2bf(float f) {  // RNE
  unsigned int u = __float_as_uint(f);
  u += 0x7fffu + ((u >> 16) & 1u);
  return (u16)(u >> 16);
}
__device__ __forceinline__ u16 f2bf_fast(float f) {  // round-half-up
  return (u16)((__float_as_uint(f) + 0x8000u) >> 16);
}
__device__ __forceinline__ float bf2f(u16 u) {
  return __uint_as_float(((unsigned int)u) << 16);
}

__device__ __forceinline__ f32x16 mfma32(bf16x8 a, bf16x8 b, f32x16 c) {
  return __builtin_amdgcn_mfma_f32_32x32x16_bf16(a, b, c, 0, 0, 0);
}
__device__ __forceinline__ f32x16 mfma32f8(long a, long b, f32x16 c) {
  return __builtin_amdgcn_mfma_f32_32x32x16_fp8_fp8(a, b, c, 0, 0, 0);
}

// async global->LDS, 16B/lane, dest = wave-uniform base + lane*16
__device__ __forceinline__ void gl_lds16(const u8* g, u8* l) {
  __builtin_amdgcn_global_load_lds(
      (const __attribute__((address_space(1))) unsigned int*)g,
      (__attribute__((address_space(3))) unsigned int*)l, 16, 0, 0);
}

#define ROWMAP(r, half) (((r) & 3) + 8 * ((r) >> 2) + 4 * (half))

// sqrt((1/16)*log2e): folded into BOTH q and k -> softmax is bare exp2,
// and fp8 values sit in e4m3 normal range.
#define QK_SCALE 0.30028063f

// ---------------- weights fp32 -> bf16 (once, tiny) ----------------
__global__ __launch_bounds__(256) void k_prep(const float* __restrict__ wq,
                                              const float* __restrict__ wo,
                                              u16* __restrict__ Wqb,
                                              u16* __restrict__ Wob) {
  int i = blockIdx.x * 256 + threadIdx.x;  // 65536 float4 chunks
  const int QCH = (3 * C_ * C_) / 4;
  const float* src = (i < QCH) ? wq + (size_t)i * 4 : wo + (size_t)(i - QCH) * 4;
  u16* dst = (i < QCH) ? Wqb + (size_t)i * 4 : Wob + (size_t)(i - QCH) * 4;
  f32x4 v = *(const f32x4*)src;
  u16x4 r = {f2bf(v[0]), f2bf(v[1]), f2bf(v[2]), f2bf(v[3])};
  *(u16x4*)dst = r;
}

// ---------------- QKV projection -> fp8 Q/K/V, coalesced stores -------------
// grid (64 n0, 2 yb, 4 b). Round mt: all 4 waves cover 128 contiguous outputs
// (uniform seg). Results staged fp8 in LDS, stored as 128B lines (Q/K) /
// 64B sectors (V).
__global__ __launch_bounds__(256, 2) void k_qkv(
    const u16* __restrict__ Wqb, const float* __restrict__ bias,
    const float* __restrict__ x, u8* __restrict__ Qt, u8* __restrict__ Kt,
    u8* __restrict__ Vn) {
  __shared__ u16 Xs[64 * 264];
  __shared__ u8 Sg[9216];  // SQ: [64 pix][136] or SV: [128 c][72]
  const int b = blockIdx.z, yb = blockIdx.y, n0 = blockIdx.x * 64;
  const int t = threadIdx.x, w = t >> 6, lane = t & 63;
  const int l32 = lane & 31, half = lane >> 5;
#pragma unroll
  for (int it = 0; it < 16; ++it) {
    int chunk = t + 256 * it;
    int row = chunk >> 4;   // c 0..255
    int col = chunk & 15;   // float4 along n
    f32x4 v = *(const f32x4*)(x + (((size_t)b * C_ + row) * N_ + n0 + col * 4));
#pragma unroll
    for (int i = 0; i < 4; ++i) Xs[(col * 4 + i) * 264 + row] = f2bf(v[i]);
  }
  __syncthreads();

  BF8 xf[2][16];
#pragma unroll
  for (int nt = 0; nt < 2; ++nt)
#pragma unroll
    for (int ks = 0; ks < 16; ++ks)
      xf[nt][ks].u =
          *(const u16x8*)&Xs[(nt * 32 + l32) * 264 + ks * 16 + half * 8];

#pragma unroll
  for (int mt = 0; mt < 3; ++mt) {
    const int omr = yb * 384 + mt * 128;  // 128-wide tile, uniform seg
    const int seg = omr >> 8;             // 0=Q 1=K 2=V
    const int ow = omr + w * 32;          // this wave's 32 outputs
    BF8 wf[16];
    const u16* wrow = Wqb + (size_t)(ow + l32) * C_ + half * 8;
#pragma unroll
    for (int ks = 0; ks < 16; ++ks) wf[ks].u = *(const u16x8*)(wrow + ks * 16);

    f32x16 a0, a1;
#pragma unroll
    for (int r = 0; r < 16; ++r) a0[r] = a1[r] = 0.f;

    if (seg < 2) {
      // A = wf (m=o), B = xf (n=pix): regs -> o = ow+ROWMAP, lane -> pix
#pragma unroll
      for (int ks = 0; ks < 16; ++ks) {
        a0 = mfma32(wf[ks].b, xf[0][ks].b, a0);
        a1 = mfma32(wf[ks].b, xf[1][ks].b, a1);
      }
#pragma unroll
      for (int nt = 0; nt < 2; ++nt) {
        const f32x16& a = nt ? a1 : a0;
#pragma unroll
        for (int g = 0; g < 4; ++g) {
          f32x4 bv = *(const f32x4*)&bias[ow + 8 * g + 4 * half];
          float v0 = (a[4 * g + 0] + bv[0]) * QK_SCALE;
          float v1 = (a[4 * g + 1] + bv[1]) * QK_SCALE;
          float v2 = (a[4 * g + 2] + bv[2]) * QK_SCALE;
          float v3 = (a[4 * g + 3] + bv[3]) * QK_SCALE;
          int pkw = __builtin_amdgcn_cvt_pk_fp8_f32(v0, v1, 0, false);
          pkw = __builtin_amdgcn_cvt_pk_fp8_f32(v2, v3, pkw, true);
          *(int*)&Sg[(nt * 32 + l32) * 136 + w * 32 + 8 * g + 4 * half] = pkw;
        }
      }
      __syncthreads();
      {  // full-128B-line stores: Qt/Kt[b][pix][ol..ol+128)
        u8* dst = ((seg == 0) ? Qt : Kt) + ((size_t)b * N_ + n0) * C_ +
                  (omr & 255);
        int row = t >> 2, cb = t & 3;
        u8x16 q0 = *(const u8x16*)&Sg[row * 136 + cb * 32];
        u8x16 q1 = *(const u8x16*)&Sg[row * 136 + cb * 32 + 16];
        u8* d = dst + (size_t)row * C_ + cb * 32;
        *(u8x16*)d = q0;
        *(u8x16*)(d + 16) = q1;
      }
      __syncthreads();
    } else {
      // A = xf (m=pix), B = wf (n=c): regs -> pix = ROWMAP, lane -> c
#pragma unroll
      for (int ks = 0; ks < 16; ++ks) {
        a0 = mfma32(xf[0][ks].b, wf[ks].b, a0);
        a1 = mfma32(xf[1][ks].b, wf[ks].b, a1);
      }
      const float bvv = bias[ow + l32];
#pragma unroll
      for (int nt = 0; nt < 2; ++nt) {
        const f32x16& a = nt ? a1 : a0;
#pragma unroll
        for (int g = 0; g < 4; ++g) {
          float v0 = a[4 * g + 0] + bvv, v1 = a[4 * g + 1] + bvv;
          float v2 = a[4 * g + 2] + bvv, v3 = a[4 * g + 3] + bvv;
          int pkw = __builtin_amdgcn_cvt_pk_fp8_f32(v0, v1, 0, false);
          pkw = __builtin_amdgcn_cvt_pk_fp8_f32(v2, v3, pkw, true);
          *(int*)&Sg[(w * 32 + l32) * 72 + nt * 32 + 8 * g + 4 * half] = pkw;
        }
      }
      __syncthreads();
      {  // Vn[b][c][n0..n0+64): 64B sectors
        u8* dst = Vn + ((size_t)b * C_ + (omr - 512)) * N_ + n0;
        int row = t >> 1, ch = t & 1;
        u8x16 q0 = *(const u8x16*)&Sg[row * 72 + ch * 32];
        u8x16 q1 = *(const u8x16*)&Sg[row * 72 + ch * 32 + 16];
        u8* d = dst + (size_t)row * N_ + ch * 32;
        *(u8x16*)d = q0;
        *(u8x16*)(d + 16) = q1;
      }
      __syncthreads();
    }
  }
}

// ---------------- out-proj + split-combine + bias + residual ----------------
__global__ __launch_bounds__(256, 2) void k_out(
    const u16* __restrict__ Wob, const float* __restrict__ bias,
    const float* __restrict__ xres, float* __restrict__ outp,
    const u16* __restrict__ Op, const float* __restrict__ Ml) {
  __shared__ u16 Xs[32 * 264];
  const int b = blockIdx.y, n0 = blockIdx.x * 32;
  const int t = threadIdx.x, w = t >> 6, lane = t & 63;
  const int l32 = lane & 31, half = lane >> 5;
  const size_t TEN = (size_t)B_ * N_ * C_;
  const size_t BN = (size_t)B_ * N_;
#pragma unroll
  for (int it = 0; it < 4; ++it) {
    int chunk = t + 256 * it;
    int row = chunk >> 5, col = chunk & 31;
    size_t rowg = (size_t)b * N_ + n0 + row;
    float f = 1.0f / (Ml[rowg] + Ml[BN + rowg] + Ml[2 * BN + rowg] +
                      Ml[3 * BN + rowg]);
    size_t base = rowg * C_ + col * 8;
    u16x8 a0 = *(const u16x8*)&Op[base];
    u16x8 a1 = *(const u16x8*)&Op[TEN + base];
    u16x8 rr;
#pragma unroll
    for (int i = 0; i < 8; ++i) rr[i] = f2bf((bf2f(a0[i]) + bf2f(a1[i])) * f);
    *(u16x8*)&Xs[row * 264 + col * 8] = rr;
  }
  __syncthreads();

  BF8 xf[16];
#pragma unroll
  for (int ks = 0; ks < 16; ++ks)
    xf[ks].u = *(const u16x8*)&Xs[l32 * 264 + ks * 16 + half * 8];

#pragma unroll
  for (int mt = 0; mt < 2; ++mt) {
    const int om = w * 64 + mt * 32;
    BF8 wf[16];
    const u16* wrow = Wob + (size_t)(om + l32) * C_ + half * 8;
#pragma unroll
    for (int ks = 0; ks < 16; ++ks) wf[ks].u = *(const u16x8*)(wrow + ks * 16);
    f32x16 a;
#pragma unroll
    for (int r = 0; r < 16; ++r) a[r] = 0.f;
#pragma unroll
    for (int ks = 0; ks < 16; ++ks) a = mfma32(wf[ks].b, xf[ks].b, a);
#pragma unroll
    for (int r = 0; r < 16; ++r) {
      int oc = om + ROWMAP(r, half);
      size_t idx = ((size_t)b * C_ + oc) * N_ + n0 + l32;
      outp[idx] = a[r] + bias[oc] + xres[idx];
    }
  }
}

// ---------------- flash attention: fp8 MFMA, global_load_lds staging,
// XOR-swizzled LDS (no padding), shfl P-transform, 1 barrier/iter ----------
// raw layout: K[2] @ 0/16384 (64 rows x 256B, granule g stored at g^(row&15));
//             V[2] @ 32768/49152 (256 rows x 64B, granule g at g^((c>>1)&3)).
// Epilogue reuses raw as u16 M[2][64][264] (67584 B).
__global__ __launch_bounds__(256, 2) void k_attn(const u8* __restrict__ Qt,
                                                 const u8* __restrict__ Kt,
                                                 const u8* __restrict__ Vn,
                                                 u16* __restrict__ Op,
                                                 float* __restrict__ Ml) {
  __shared__ u8 raw[67584];
  const int id = blockIdx.x;
  const int xcd = id & 7;
  const int b = xcd >> 1;
  const int jh = xcd & 1;
  const int i0 = (id >> 3) * 64;
  const int t = threadIdx.x, w = t >> 6, lane = t & 63;
  const int l32 = lane & 31, half = lane >> 5;
  const int mh = w >> 1, jh2 = w & 1;

  long qf[16];
  {
    const u8* qrow = Qt + ((size_t)b * N_ + i0 + mh * 32 + l32) * C_ + half * 8;
#pragma unroll
    for (int ks = 0; ks < 16; ++ks) qf[ks] = *(const long*)(qrow + ks * 16);
  }
  f32x16 o[8];
#pragma unroll
  for (int ct = 0; ct < 8; ++ct)
#pragma unroll
    for (int r = 0; r < 16; ++r) o[ct][r] = 0.f;
  float l_i = 0.f;

  const u8* kbase = Kt + (size_t)b * N_ * C_;
  const u8* vbase = Vn + (size_t)b * (size_t)C_ * N_;
  const int jbeg = jh * (N_ / 2), jend = jbeg + N_ / 2;

  const int kR = lane >> 4, kG = lane & 15;  // K: 4 rows/call, granule
  const int vR = lane >> 2, vG = lane & 3;   // V: 16 rows/call, granule

  auto stage = [&](int j0, int buf) {
#pragma unroll
    for (int it = 0; it < 4; ++it) {
      int rloc = w * 16 + it * 4 + kR;  // 0..63
      const u8* g =
          kbase + (size_t)(j0 + rloc) * C_ + ((kG ^ (rloc & 15)) << 4);
      gl_lds16(g, raw + buf * 16384 + (w * 16 + it * 4) * 256);
    }
#pragma unroll
    for (int it = 0; it < 4; ++it) {
      int cloc = w * 64 + it * 16 + vR;  // 0..255
      const u8* g =
          vbase + (size_t)cloc * N_ + j0 + ((vG ^ ((cloc >> 1) & 3)) << 4);
      gl_lds16(g, raw + 32768 + buf * 16384 + (w * 64 + it * 16) * 64);
    }
  };

  stage(jbeg, 0);
  __syncthreads();
  int cur = 0;

  for (int j0 = jbeg; j0 < jend; j0 += 64) {
    int jn = j0 + 64;
    if (jn >= jend) jn = jbeg;  // last iter: dummy (valid) prefetch
    stage(jn, cur ^ 1);

    // S^T 32x32: lane = q-row l32, regs = j-local = 8g+4half+i
    f32x16 s;
#pragma unroll
    for (int r = 0; r < 16; ++r) s[r] = 0.f;
    {
      const int jrow = jh2 * 32 + l32;
      const u8* krowp = raw + cur * 16384 + jrow * 256 + half * 8;
#pragma unroll
      for (int ks = 0; ks < 16; ++ks) {
        long kf = *(const long*)(krowp + ((ks ^ (jrow & 15)) << 4));
        s = mfma32f8(kf, qf[ks], s);
      }
    }

    // p = exp2(s) -> fp8 dwords pd[g] (bytes i <-> j = 8g+4half+i)
    int pd[4];
    float tile_sum = 0.f;
#pragma unroll
    for (int g = 0; g < 4; ++g) {
      float p0 = exp2f(s[4 * g + 0]), p1 = exp2f(s[4 * g + 1]);
      float p2 = exp2f(s[4 * g + 2]), p3 = exp2f(s[4 * g + 3]);
      tile_sum += (p0 + p1) + (p2 + p3);
      int w0 = __builtin_amdgcn_cvt_pk_fp8_f32(p0, p1, 0, false);
      pd[g] = __builtin_amdgcn_cvt_pk_fp8_f32(p2, p3, w0, true);
    }
    tile_sum += __shfl_xor(tile_sum, 32);
    l_i += tile_sum;

    // B-frag for PV chunk kc: bytes <-> j = 16kc + 8half + {0..7};
    // own dword pd[2kc+half] + partner's (lane^32) give the two halves.
    long pb[2];
#pragma unroll
    for (int kc = 0; kc < 2; ++kc) {
      int own = pd[2 * kc + half];
      int oth = __shfl_xor(pd[2 * kc + (half ^ 1)], 32);
      unsigned lo = half ? (unsigned)oth : (unsigned)own;
      unsigned hi = half ? (unsigned)own : (unsigned)oth;
      pb[kc] = (long)(((unsigned long long)hi << 32) | lo);
    }

    // O^T += V^T P^T: A = Vs[c][j] frag, B = pb; D lane = q-row, regs = c
    {
      const u8* vbp = raw + 32768 + cur * 16384;
      const int sw = (l32 >> 1) & 3;
#pragma unroll
      for (int ct = 0; ct < 8; ++ct) {
        const u8* vrowp = vbp + (ct * 32 + l32) * 64 + half * 8;
#pragma unroll
        for (int kc = 0; kc < 2; ++kc) {
          long vf = *(const long*)(vrowp + (((2 * jh2 + kc) ^ sw) << 4));
          o[ct] = mfma32f8(vf, pb[kc], o[ct]);
        }
      }
    }

    __syncthreads();  // drains global_load_lds (vmcnt) + LDS reads done
    cur ^= 1;
  }

  // ---- merge jh2 partials via LDS (reuses raw), coalesced Op store
  float* ml = Ml + ((size_t)(jh * 2 + jh2) * B_ + b) * N_;
  if (lane < 32) ml[i0 + mh * 32 + l32] = l_i;

  u16* M = (u16*)raw;  // [2][64][264]
#pragma unroll
  for (int ct = 0; ct < 8; ++ct)
#pragma unroll
    for (int g = 0; g < 4; ++g) {
      u16x4 pkv = {f2bf_fast(o[ct][4 * g + 0]), f2bf_fast(o[ct][4 * g + 1]),
                   f2bf_fast(o[ct][4 * g + 2]), f2bf_fast(o[ct][4 * g + 3])};
      *(u16x4*)&M[jh2 * (64 * 264) + (mh * 32 + l32) * 264 + ct * 32 + 8 * g +
                  4 * half] = pkv;
    }
  __syncthreads();

  u16* op = Op + ((size_t)jh * B_ + b) * (size_t)N_ * C_ + (size_t)i0 * C_;
  const int row = t >> 2, cb = t & 3;
#pragma unroll
  for (int k = 0; k < 8; ++k) {
    u16x8 m0 = *(const u16x8*)&M[row * 264 + cb * 64 + k * 8];
    u16x8 m1 = *(const u16x8*)&M[64 * 264 + row * 264 + cb * 64 + k * 8];
    u16x8 rr;
#pragma unroll
    for (int i = 0; i < 8; ++i) rr[i] = f2bf_fast(bf2f(m0[i]) + bf2f(m1[i]));
    *(u16x8*)&op[(size_t)row * C_ + cb * 64 + k * 8] = rr;
  }
}

extern "C" void kernel_launch(void* const* d_in, const int* in_sizes, int n_in,
                              void* d_out, int out_size, void* d_ws,
                              size_t ws_size, hipStream_t stream) {
  (void)in_sizes; (void)n_in; (void)out_size; (void)ws_size;
  const float* x = (const float*)d_in[0];
  const float* w_qkv = (const float*)d_in[1];
  const float* b_qkv = (const float*)d_in[2];
  const float* w_out = (const float*)d_in[3];
  const float* b_out = (const float*)d_in[4];
  float* outp = (float*)d_out;

  const size_t TENS = (size_t)B_ * N_ * C_;  // 4M elems
  u8* Qt = (u8*)d_ws;        // [B][N][C] fp8 (scaled)      4 MB
  u8* Kt = Qt + TENS;        // [B][N][C] fp8 (scaled)      4 MB
  u8* Vn = Kt + TENS;        // [B][C][N] fp8               4 MB
  u16* Op = (u16*)(Vn + TENS);  // [2][B][N][C] bf16       16 MB
  float* Ml = (float*)(Op + 2 * TENS);          // [4][B][N]  256 KB
  u16* Wqb = (u16*)(Ml + 4 * (size_t)B_ * N_);  // [3C][C]    384 KB
  u16* Wob = Wqb + 3 * C_ * C_;                 // [C][C]     128 KB

  k_prep<<<dim3(256), 256, 0, stream>>>(w_qkv, w_out, Wqb, Wob);
  k_qkv<<<dim3(64, 2, 4), 256, 0, stream>>>(Wqb, b_qkv, x, Qt, Kt, Vn);
  k_attn<<<dim3(512), 256, 0, stream>>>(Qt, Kt, Vn, Op, Ml);
  k_out<<<dim3(128, 4), 256, 0, stream>>>(Wob, b_out, x, outp, Op, Ml);
}